// Round 8
// baseline (4002.592 us; speedup 1.0000x reference)
//
#include <hip/hip_runtime.h>
#include <hip/hip_bf16.h>
#include <math.h>

typedef __hip_bfloat16 bf16;
typedef unsigned int u32;

__device__ __forceinline__ float b2f(bf16 x){ return __bfloat162float(x); }
__device__ __forceinline__ bf16  f2b(float x){ return __float2bfloat16(x); }
__device__ __forceinline__ float lo16(u32 u){ return __uint_as_float(u << 16); }
__device__ __forceinline__ float hi16(u32 u){ return __uint_as_float(u & 0xFFFF0000u); }
// float -> bf16 bits with round-to-nearest-even
__device__ __forceinline__ u32 bfbits(float x){
    u32 u = __float_as_uint(x);
    return (u + 0x7FFFu + ((u >> 16) & 1u)) >> 16;
}

#define RSQRT8 0.35355339059327373f
#define G_STEP (10.0f/19.0f)
#define G_COEF (-0.5f/(G_STEP*G_STEP))

// butterfly layout involution: lane l holds head PERM4(l&15); PERM4 is self-inverse
__device__ __forceinline__ constexpr int PERM4(int h){
    return ((h&1)<<3) | ((h&2)<<1) | ((h&4)>>1) | ((h&8)>>3);
}

// fast atan2 for y >= 0 (result in [0, pi]); poly max err ~1.6e-6 rad
__device__ __forceinline__ float fast_atan2(float y, float x){
    float ax = fabsf(x);
    float mn = fminf(y, ax), mx = fmaxf(y, ax);
    float t = mn / fmaxf(mx, 1e-30f);
    float s = t*t;
    float p = t * (0.99997726f + s*(-0.33262347f + s*(0.19354346f +
              s*(-0.11643287f + s*(0.05265332f + s*(-0.01172120f))))));
    float r = (y > ax) ? (1.5707963267948966f - p) : p;
    r = (x < 0.f) ? (3.14159265358979323f - r) : r;
    return r;
}

// inputs are PROVEN f32

// ---------------- seg starts (idx_ji sorted) + work-steal counter init -------
__global__ void seg_start_kernel(const int* __restrict__ idx_ji, int T,
                                 int* __restrict__ seg, int E, int* __restrict__ ctr)
{
    int e = blockIdx.x * blockDim.x + threadIdx.x;
    if (blockIdx.x == 0 && threadIdx.x == 0) *ctr = 0;
    if (e > E) return;
    int lo = 0, hi = T;
    while (lo < hi) { int mid = (lo + hi) >> 1; if (idx_ji[mid] < e) lo = mid + 1; else hi = mid; }
    seg[e] = lo;
}

__global__ void marker_kernel(float* out, int n){
    int i = blockIdx.x * blockDim.x + threadIdx.x;
    if (i < n) out[i] = 12345.0f;
}

// ---------------- pack W2 matrices to bf16-pair layouts (L2-resident) --------
__global__ void pack_w2(const float* __restrict__ Wk2, const float* __restrict__ Wv2,
                        u32* __restrict__ kw2t, u32* __restrict__ vw2t)
{
    int idx = blockIdx.x*256 + threadIdx.x;
    if (idx >= 8192) return;
    int c = idx >> 6, p = idx & 63;
    kw2t[idx] = bfbits(Wk2[(size_t)(2*p)*128 + c]) | (bfbits(Wk2[(size_t)(2*p+1)*128 + c]) << 16);
    int j = idx >> 7, o = idx & 127;
    vw2t[idx] = bfbits(Wv2[(size_t)(2*j)*128 + o]) | (bfbits(Wv2[(size_t)(2*j+1)*128 + o]) << 16);
}

// ---------------- q = MLP_hq(h_bond) per edge -> bf16, 4-edge batched --------
__global__ __launch_bounds__(128) void q_kernel(
    const float* __restrict__ W1, const float* __restrict__ B1,
    const float* __restrict__ G,  const float* __restrict__ Bln,
    const float* __restrict__ W2, const float* __restrict__ B2,
    const float* __restrict__ h_bond, bf16* __restrict__ qout, int E)
{
    __shared__ u32 sW[128*65];
    __shared__ float sH[16][130];
    __shared__ float sX[4][130];
    __shared__ float sRed[4][4];
    int tid = threadIdx.x; int wv = tid>>6, lane = tid&63;
    int base = blockIdx.x * 16;

    for (int idx = tid; idx < 128*128; idx += 128) {
        int i = idx >> 7, d = idx & 127;
        ((bf16*)sW)[d*130 + i] = f2b(W1[idx]);
    }
    __syncthreads();
    for (int e4 = 0; e4 < 16; e4 += 4) {
        #pragma unroll
        for (int q = 0; q < 4; ++q) {
            int e = base + e4 + q;
            sX[q][tid] = (e < E) ? h_bond[(size_t)e*128 + tid] : 0.f;
        }
        __syncthreads();
        float b1t = B1[tid];
        float ac[4] = {b1t, b1t, b1t, b1t};
        const u32* wrow = &sW[tid*65];
        #pragma unroll 4
        for (int j = 0; j < 64; ++j) {
            u32 w = wrow[j]; float wl = lo16(w), wh = hi16(w);
            #pragma unroll
            for (int q = 0; q < 4; ++q)
                ac[q] += sX[q][2*j]*wl + sX[q][2*j+1]*wh;
        }
        float s1v[4], s2v[4];
        #pragma unroll
        for (int q = 0; q < 4; ++q) { s1v[q] = ac[q]; s2v[q] = ac[q]*ac[q]; }
        #pragma unroll
        for (int m = 1; m < 64; m <<= 1) {
            #pragma unroll
            for (int q = 0; q < 4; ++q) {
                s1v[q] += __shfl_xor(s1v[q], m, 64);
                s2v[q] += __shfl_xor(s2v[q], m, 64);
            }
        }
        if (lane == 0) {
            #pragma unroll
            for (int q = 0; q < 4; ++q) { sRed[q][wv*2] = s1v[q]; sRed[q][wv*2+1] = s2v[q]; }
        }
        __syncthreads();
        float gt = G[tid], bt = Bln[tid];
        #pragma unroll
        for (int q = 0; q < 4; ++q) {
            float tot = sRed[q][0] + sRed[q][2], tot2 = sRed[q][1] + sRed[q][3];
            float mu = tot * (1.f/128.f);
            float var = fmaxf(tot2 * (1.f/128.f) - mu*mu, 0.f);
            float nv = gt * (ac[q] - mu) * rsqrtf(var + 1e-5f) + bt;
            sH[e4+q][tid] = fmaxf(nv, 0.f);
        }
        __syncthreads();
    }
    for (int idx = tid; idx < 128*128; idx += 128) {
        int i = idx >> 7, d = idx & 127;
        ((bf16*)sW)[d*130 + i] = f2b(W2[idx]);
    }
    __syncthreads();
    for (int e4 = 0; e4 < 16; e4 += 4) {
        float b2t = B2[tid];
        float ac[4] = {b2t, b2t, b2t, b2t};
        const u32* wrow = &sW[tid*65];
        #pragma unroll 4
        for (int j = 0; j < 64; ++j) {
            u32 w = wrow[j]; float wl = lo16(w), wh = hi16(w);
            #pragma unroll
            for (int q = 0; q < 4; ++q)
                ac[q] += sH[e4+q][2*j]*wl + sH[e4+q][2*j+1]*wh;
        }
        #pragma unroll
        for (int q = 0; q < 4; ++q) {
            int e = base + e4 + q;
            if (e < E) qout[(size_t)e*128 + tid] = f2b(ac[q]);
        }
    }
}

// ---------------- P1[e] = h_bond[e]@W1[0:128] + rfeat[e]@W1[128:148] -> bf16 --
// R5-proven: LDS-staged weights, 4-edge batched.
__global__ __launch_bounds__(128) void p_prep(
    const float* __restrict__ W1, const float* __restrict__ h_bond,
    const float* __restrict__ pos, const int* __restrict__ row,
    const int* __restrict__ col, bf16* __restrict__ P1, int E)
{
    __shared__ u32 sW[128*75];       // [dim][row-pair], 148 rows -> 74 pairs, stride 150 bf16
    __shared__ float sX[4][152];
    int tid = threadIdx.x;
    for (int idx = tid; idx < 148*128; idx += 128) {
        int i = idx >> 7, d = idx & 127;
        ((bf16*)sW)[d*150 + i] = f2b(W1[idx]);
    }
    __syncthreads();
    int base = blockIdx.x * 16;
    for (int e4 = 0; e4 < 16; e4 += 4) {
        #pragma unroll
        for (int q = 0; q < 4; ++q) {
            int e = base + e4 + q;
            sX[q][tid] = (e < E) ? h_bond[(size_t)e*128 + tid] : 0.f;
        }
        if (tid < 80) {
            int q = tid / 20, g = tid % 20;
            int e = base + e4 + q;
            float rf = 0.f;
            if (e < E) {
                int i0 = col[e], j0 = row[e];
                float dx = pos[(size_t)i0*3+0] - pos[(size_t)j0*3+0];
                float dy = pos[(size_t)i0*3+1] - pos[(size_t)j0*3+1];
                float dz = pos[(size_t)i0*3+2] - pos[(size_t)j0*3+2];
                float dist = sqrtf(dx*dx + dy*dy + dz*dz);
                float t = dist - (float)g * G_STEP;
                rf = __expf(G_COEF * t * t);
            }
            sX[q][128 + g] = rf;
        }
        __syncthreads();
        float acc0 = 0.f, acc1 = 0.f, acc2 = 0.f, acc3 = 0.f;
        const u32* wrow = &sW[tid*75];
        #pragma unroll 4
        for (int j = 0; j < 74; ++j) {
            u32 w = wrow[j]; float wl = lo16(w), wh = hi16(w);
            acc0 += sX[0][2*j]*wl + sX[0][2*j+1]*wh;
            acc1 += sX[1][2*j]*wl + sX[1][2*j+1]*wh;
            acc2 += sX[2][2*j]*wl + sX[2][2*j+1]*wh;
            acc3 += sX[3][2*j]*wl + sX[3][2*j+1]*wh;
        }
        int e = base + e4;
        if (e   < E) P1[(size_t)e*128     + tid] = f2b(acc0);
        if (e+1 < E) P1[(size_t)(e+1)*128 + tid] = f2b(acc1);
        if (e+2 < E) P1[(size_t)(e+2)*128 + tid] = f2b(acc2);
        if (e+3 < E) P1[(size_t)(e+3)*128 + tid] = f2b(acc3);
        __syncthreads();
    }
}

// geometry + trig identities for one triplet (suffix S)
#define GEOM(S) \
    float dt##S = ax*bx##S + ay*by##S + az*bz##S; \
    float cxx##S = ay*bz##S - az*by##S, cyy##S = az*bx##S - ax*bz##S, czz##S = ax*by##S - ay*bx##S; \
    float bb##S = cxx##S*cxx##S + cyy##S*cyy##S + czz##S*czz##S; \
    float bc##S = sqrtf(bb##S); \
    float ih##S = rsqrtf(fmaxf(dt##S*dt##S + bb##S, 1e-30f)); \
    float c1##S = dt##S * ih##S, s1##S = bc##S * ih##S; \
    float ang##S = fast_atan2(bc##S, dt##S); \
    float sh##S = sqrtf(fmaxf(0.5f*(1.f - c1##S), 0.f)); \
    float ch##S = sqrtf(fmaxf(0.5f*(1.f + c1##S), 0.f)); \
    float st3##S, ct3##S; __sincosf((1.f/3.f)*ang##S, &st3##S, &ct3##S);

// one feature: read both paths' weight pair once, 8 FMA (2 triplets x 2 paths x 2 dims)
#define FEAT(fidx, valX, valY) { \
    u32 wk_ = sWA[0][(fidx)*64 + lane]; \
    u32 wu_ = sWA[1][(fidx)*64 + lane]; \
    float wkl_ = lo16(wk_), wkh_ = hi16(wk_), wvl_ = lo16(wu_), wvh_ = hi16(wu_); \
    float fx_ = (valX), fy_ = (valY); \
    v0kX += fx_*wkl_; v1kX += fx_*wkh_; v0vX += fx_*wvl_; v1vX += fx_*wvh_; \
    v0kY += fy_*wkl_; v1kY += fy_*wkh_; v0vY += fy_*wvl_; v1vY += fy_*wvh_; }

// 7-shfl split reduction: (sum, sumsq) over 128 dims
#define LNSTATS(v0_, v1_, TOT, TOT2) { \
    float sum_ = (v0_) + (v1_), ssq_ = (v0_)*(v0_) + (v1_)*(v1_); \
    float r_ = ((lane&1) ? ssq_ : sum_) + __shfl_xor((lane&1) ? sum_ : ssq_, 1, 64); \
    r_ += __shfl_xor(r_, 2, 64);  r_ += __shfl_xor(r_, 4, 64); \
    r_ += __shfl_xor(r_, 8, 64);  r_ += __shfl_xor(r_, 16, 64); \
    r_ += __shfl_xor(r_, 32, 64); \
    float o_ = __shfl_xor(r_, 1, 64); \
    TOT = (lane&1) ? o_ : r_;  TOT2 = (lane&1) ? r_ : o_; }

#define LNAPPLY(TOT, TOT2, v0_, v1_, g_, b_, H0, H1) { \
    float mu_ = (TOT) * (1.f/128.f); \
    float var_ = fmaxf((TOT2) * (1.f/128.f) - mu_*mu_, 0.f); \
    float rs_ = rsqrtf(var_ + 1e-5f); \
    H0 = fmaxf(g_.x*((v0_)-mu_)*rs_ + b_.x, 0.f); \
    H1 = fmaxf(g_.y*((v1_)-mu_)*rs_ + b_.y, 0.f); }

// 17-shfl split-exchange butterfly: 16 reductions -> LG (head PERM4(lane&15))
#define BFLY(P, LG) { \
    float a8_[8]; \
    { int up_ = lane & 1; \
      _Pragma("unroll") \
      for (int i_ = 0; i_ < 8; ++i_) { \
        float kp_ = up_ ? P[i_+8] : P[i_]; \
        float sd_ = up_ ? P[i_]   : P[i_+8]; \
        a8_[i_] = kp_ + __shfl_xor(sd_, 1, 64); } } \
    float a4_[4]; \
    { int up_ = lane & 2; \
      _Pragma("unroll") \
      for (int i_ = 0; i_ < 4; ++i_) { \
        float kp_ = up_ ? a8_[i_+4] : a8_[i_]; \
        float sd_ = up_ ? a8_[i_]   : a8_[i_+4]; \
        a4_[i_] = kp_ + __shfl_xor(sd_, 2, 64); } } \
    float a2_[2]; \
    { int up_ = lane & 4; \
      _Pragma("unroll") \
      for (int i_ = 0; i_ < 2; ++i_) { \
        float kp_ = up_ ? a4_[i_+2] : a4_[i_]; \
        float sd_ = up_ ? a4_[i_]   : a4_[i_+2]; \
        a2_[i_] = kp_ + __shfl_xor(sd_, 4, 64); } } \
    float a1_; \
    { int up_ = lane & 8; \
      float kp_ = up_ ? a2_[1] : a2_[0]; \
      float sd_ = up_ ? a2_[0] : a2_[1]; \
      a1_ = kp_ + __shfl_xor(sd_, 8, 64); } \
    a1_ += __shfl_xor(a1_, 16, 64); \
    a1_ += __shfl_xor(a1_, 32, 64); \
    LG = a1_ * RSQRT8; }

// ---------------- fused: logits + online softmax + v-path + projection -------
// R8: PERSISTENT WORK-STEALING WAVES. R7 showed 22% time-avg occupancy vs 50%
// theoretical (VGPR 104, LDS 23KB): one-edge-per-wave blocks retire unevenly
// (segments ~Poisson(8)) and the machine runs partially drained. Now: 1024
// resident blocks (4/CU), each wave atomically grabs edge IDs -> no retire
// churn, near-perfect balance. Also: gaussian rf computed once per edge for
// both k/v paths (-20 expf/edge).
__global__ __launch_bounds__(256, 2)
void fused_kernel(
    const u32* __restrict__ kw2t, const u32* __restrict__ vw2t,
    const float* __restrict__ Wk1, const float* __restrict__ Bk1,
    const float* __restrict__ Gkg, const float* __restrict__ Bkln,
    const float* __restrict__ Wv1, const float* __restrict__ Bv1,
    const float* __restrict__ Gvg, const float* __restrict__ Bvln,
    const float* __restrict__ B2v,
    const bf16* __restrict__ qf, const bf16* __restrict__ P1k, const bf16* __restrict__ P1v,
    const float* __restrict__ pos, const int* __restrict__ seg,
    const int* __restrict__ idx_kj, const int* __restrict__ idx_k,
    const int* __restrict__ row, const int* __restrict__ col,
    int* __restrict__ ctr, float* __restrict__ out, int E)
{
    __shared__ u32 sS[4][16*66];     // epilogue staging; loop-time overlay holds Gk
    __shared__ u32 sWA[2][11*64];    // deduped angular weight pairs: [path][f][lane]
    __shared__ float2 sEx[4][16];    // per-wave (exX, exY) per head
    int tid = threadIdx.x, lane = tid & 63, wv = tid >> 6;

    // block-cooperative populate of sWA. Feature order:
    // {ang, s1, s2, s3, sh, st3, c1, c2, c3, ch, ct3}; s1 at {1,4}, c1 at {7,10} folded.
    if (tid < 128) {
        int path = tid >> 6, l = tid & 63;
        const float* W1full = path ? Wv1 : Wk1;
        const float2* wap = (const float2*)(W1full + (size_t)168*128);
        float2 w0  = wap[ 0*64 + l];
        float2 w1  = wap[ 1*64 + l];
        float2 w2  = wap[ 2*64 + l];
        float2 w3  = wap[ 3*64 + l];
        float2 w4  = wap[ 4*64 + l];
        float2 w5  = wap[ 5*64 + l];
        float2 w6  = wap[ 6*64 + l];
        float2 w7  = wap[ 7*64 + l];
        float2 w8  = wap[ 8*64 + l];
        float2 w9  = wap[ 9*64 + l];
        float2 w10 = wap[10*64 + l];
        float2 w11 = wap[11*64 + l];
        float2 w12 = wap[12*64 + l];
        u32* dst = &sWA[path][0];
        dst[ 0*64 + l] = bfbits(w0.x)       | (bfbits(w0.y)       << 16);
        dst[ 1*64 + l] = bfbits(w1.x+w4.x)  | (bfbits(w1.y+w4.y)  << 16);
        dst[ 2*64 + l] = bfbits(w2.x)       | (bfbits(w2.y)       << 16);
        dst[ 3*64 + l] = bfbits(w3.x)       | (bfbits(w3.y)       << 16);
        dst[ 4*64 + l] = bfbits(w5.x)       | (bfbits(w5.y)       << 16);
        dst[ 5*64 + l] = bfbits(w6.x)       | (bfbits(w6.y)       << 16);
        dst[ 6*64 + l] = bfbits(w7.x+w10.x) | (bfbits(w7.y+w10.y) << 16);
        dst[ 7*64 + l] = bfbits(w8.x)       | (bfbits(w8.y)       << 16);
        dst[ 8*64 + l] = bfbits(w9.x)       | (bfbits(w9.y)       << 16);
        dst[ 9*64 + l] = bfbits(w11.x)      | (bfbits(w11.y)      << 16);
        dst[10*64 + l] = bfbits(w12.x)      | (bfbits(w12.y)      << 16);
    }
    __syncthreads();                 // ONLY barrier; before the steal loop

    int perm = ((lane&1)<<3) | ((lane&2)<<1) | ((lane&4)>>1) | ((lane&8)>>3);
    const u32* p1ku = (const u32*)P1k;
    const u32* p1vu = (const u32*)P1v;

    float2 b1k = ((const float2*)Bk1)[lane];
    float2 gk  = ((const float2*)Gkg)[lane];
    float2 bk  = ((const float2*)Bkln)[lane];
    float2 b1v = ((const float2*)Bv1)[lane];
    float2 gv  = ((const float2*)Gvg)[lane];
    float2 bv  = ((const float2*)Bvln)[lane];

    for (;;) {
        // ---- steal one edge ----
        int e;
        if (lane == 0) e = atomicAdd(ctr, 1);
        e = __builtin_amdgcn_readfirstlane(__shfl(e, 0, 64));
        if (e >= E) break;
        int s0 = __builtin_amdgcn_readfirstlane(seg[e]);
        int s1 = __builtin_amdgcn_readfirstlane(seg[e+1]);
        if (s1 <= s0) { out[(size_t)e*128 + lane] = 0.f; out[(size_t)e*128 + 64 + lane] = 0.f; continue; }

        int i0 = __builtin_amdgcn_readfirstlane(col[e]);
        int j0 = __builtin_amdgcn_readfirstlane(row[e]);
        float pix = pos[(size_t)i0*3+0], piy = pos[(size_t)i0*3+1], piz = pos[(size_t)i0*3+2];
        float pjx = pos[(size_t)j0*3+0], pjy = pos[(size_t)j0*3+1], pjz = pos[(size_t)j0*3+2];
        float dxx = pix-pjx, dyy = piy-pjy, dzz = piz-pjz;
        float dist = sqrtf(dxx*dxx + dyy*dyy + dzz*dzz);

        // P2 pre-act for BOTH paths with shared rf (one expf per gaussian)
        float P2ak = b1k.x, P2bk = b1k.y, P2av = b1v.x, P2bv = b1v.y;
        {
            const float2* wbk = (const float2*)(Wk1 + (size_t)148*128);
            const float2* wbv = (const float2*)(Wv1 + (size_t)148*128);
            for (int g2 = 0; g2 < 20; ++g2) {
                float tg = dist - (float)g2 * G_STEP;
                float rf = __expf(G_COEF * tg * tg);
                float2 wk = wbk[g2*64 + lane];
                float2 wu = wbv[g2*64 + lane];
                P2ak += rf * wk.x; P2bk += rf * wk.y;
                P2av += rf * wu.x; P2bv += rf * wu.y;
            }
        }

        // Gk[h] packed bf16 pair -> per-wave LDS (overlay on sS; loop-only lifetime)
        u32* sGkw = &sS[wv][0];
        {
            const u32* qrow = (const u32*)(qf + (size_t)e*128);
            #pragma unroll
            for (int h = 0; h < 16; ++h) {
                float g0 = 0.f, g1 = 0.f;
                #pragma unroll
                for (int j = 0; j < 4; ++j) {
                    u32 qp = qrow[h*4 + j];
                    float ql = lo16(qp), qh = hi16(qp);
                    u32 w0 = kw2t[(h*8 + 2*j)*64 + lane];
                    u32 w1 = kw2t[(h*8 + 2*j + 1)*64 + lane];
                    g0 += ql*lo16(w0) + qh*lo16(w1);
                    g1 += ql*hi16(w0) + qh*hi16(w1);
                }
                sGkw[h*64 + lane] = bfbits(g0) | (bfbits(g1) << 16);
            }
        }

        float S0[16], S1[16];
        #pragma unroll
        for (int h = 0; h < 16; ++h) { S0[h] = 0.f; S1[h] = 0.f; }
        float m = -1e30f, sden = 0.f;
        float ax = pjx-pix, ay = pjy-piy, az = pjz-piz;

        // 2-ahead prefetch state for triplet pair (X, Y)
        int tB0 = (s0+1 < s1) ? s0+1 : s0;
        int kjX = __builtin_amdgcn_readfirstlane(idx_kj[s0]);
        int knX = __builtin_amdgcn_readfirstlane(idx_k[s0]);
        int kjY = __builtin_amdgcn_readfirstlane(idx_kj[tB0]);
        int knY = __builtin_amdgcn_readfirstlane(idx_k[tB0]);
        u32 fppkX = p1ku[(size_t)kjX*64 + lane], fppvX = p1vu[(size_t)kjX*64 + lane];
        u32 fppkY = p1ku[(size_t)kjY*64 + lane], fppvY = p1vu[(size_t)kjY*64 + lane];
        float fpkxX = pos[(size_t)knX*3+0], fpkyX = pos[(size_t)knX*3+1], fpkzX = pos[(size_t)knX*3+2];
        float fpkxY = pos[(size_t)knY*3+0], fpkyY = pos[(size_t)knY*3+1], fpkzY = pos[(size_t)knY*3+2];

        for (int t = s0; t < s1; t += 2) {
            const bool twoY = (t+1 < s1);
            u32 ppkX = fppkX, ppvX = fppvX, ppkY = fppkY, ppvY = fppvY;
            float bxX = fpkxX-pix, byX = fpkyX-piy, bzX = fpkzX-piz;
            float bxY = fpkxY-pix, byY = fpkyY-piy, bzY = fpkzY-piz;
            int tn0 = (t+2 < s1) ? t+2 : s1-1;
            int tn1 = (t+3 < s1) ? t+3 : s1-1;
            kjX = __builtin_amdgcn_readfirstlane(idx_kj[tn0]);
            knX = __builtin_amdgcn_readfirstlane(idx_k[tn0]);
            kjY = __builtin_amdgcn_readfirstlane(idx_kj[tn1]);
            knY = __builtin_amdgcn_readfirstlane(idx_k[tn1]);
            fppkX = p1ku[(size_t)kjX*64 + lane]; fppvX = p1vu[(size_t)kjX*64 + lane];
            fppkY = p1ku[(size_t)kjY*64 + lane]; fppvY = p1vu[(size_t)kjY*64 + lane];
            fpkxX = pos[(size_t)knX*3+0]; fpkyX = pos[(size_t)knX*3+1]; fpkzX = pos[(size_t)knX*3+2];
            fpkxY = pos[(size_t)knY*3+0]; fpkyY = pos[(size_t)knY*3+1]; fpkzY = pos[(size_t)knY*3+2];

            GEOM(X);
            GEOM(Y);

            float v0kX = P2ak + lo16(ppkX), v1kX = P2bk + hi16(ppkX);
            float v0vX = P2av + lo16(ppvX), v1vX = P2bv + hi16(ppvX);
            float v0kY = P2ak + lo16(ppkY), v1kY = P2bk + hi16(ppkY);
            float v0vY = P2av + lo16(ppvY), v1vY = P2bv + hi16(ppvY);

            FEAT(0,  angX, angY);
            FEAT(1,  s1X,  s1Y);
            FEAT(2,  2.f*s1X*c1X, 2.f*s1Y*c1Y);
            FEAT(3,  s1X*(3.f - 4.f*s1X*s1X), s1Y*(3.f - 4.f*s1Y*s1Y));
            FEAT(4,  shX,  shY);
            FEAT(5,  st3X, st3Y);
            FEAT(6,  c1X,  c1Y);
            FEAT(7,  1.f - 2.f*s1X*s1X, 1.f - 2.f*s1Y*s1Y);
            FEAT(8,  c1X*(4.f*c1X*c1X - 3.f), c1Y*(4.f*c1Y*c1Y - 3.f));
            FEAT(9,  chX,  chY);
            FEAT(10, ct3X, ct3Y);

            float totKX, tot2KX, totVX, tot2VX, totKY, tot2KY, totVY, tot2VY;
            LNSTATS(v0kX, v1kX, totKX, tot2KX);
            LNSTATS(v0vX, v1vX, totVX, tot2VX);
            LNSTATS(v0kY, v1kY, totKY, tot2KY);
            LNSTATS(v0vY, v1vY, totVY, tot2VY);
            float h0kX, h1kX, h0vX, h1vX, h0kY, h1kY, h0vY, h1vY;
            LNAPPLY(totKX, tot2KX, v0kX, v1kX, gk, bk, h0kX, h1kX);
            LNAPPLY(totVX, tot2VX, v0vX, v1vX, gv, bv, h0vX, h1vX);
            LNAPPLY(totKY, tot2KY, v0kY, v1kY, gk, bk, h0kY, h1kY);
            LNAPPLY(totVY, tot2VY, v0vY, v1vY, gv, bv, h0vY, h1vY);

            float pX[16], pY[16];
            #pragma unroll
            for (int h = 0; h < 16; ++h) {
                u32 g = sGkw[h*64 + lane];
                float gl = lo16(g), gh = hi16(g);
                pX[h] = h0kX*gl + h1kX*gh;
                pY[h] = h0kY*gl + h1kY*gh;
            }
            float lgX, lgY;
            BFLY(pX, lgX);
            BFLY(pY, lgY);

            float mx = fmaxf(lgX, lgY);
            if (__any(mx > m + 8.f)) {
                float nm = fmaxf(m, mx);
                float fac = __expf(m - nm);
                sden *= fac; m = nm;
                #pragma unroll
                for (int h = 0; h < 16; ++h) {
                    float fh = __shfl(fac, PERM4(h), 64);
                    S0[h] *= fh; S1[h] *= fh;
                }
            }
            float exX = __expf(lgX - m);
            float exY = twoY ? __expf(lgY - m) : 0.f;   // masked tail: no double count
            sden += exX + exY;
            if (lane < 16) sEx[wv][perm] = make_float2(exX, exY);
            #pragma unroll
            for (int h = 0; h < 16; ++h) {
                float2 eh = sEx[wv][h];
                S0[h] += eh.x*h0vX + eh.y*h0vY;
                S1[h] += eh.x*h1vX + eh.y*h1vY;
            }
        }

        // normalize by softmax denominator while staging S as bf16 pairs
        float inv = 1.f / sden;
        #pragma unroll
        for (int h = 0; h < 16; ++h) {
            float sc = __shfl(inv, PERM4(h), 64);
            sS[wv][h*66 + lane] = bfbits(S0[h]*sc) | (bfbits(S1[h]*sc) << 16);
        }
        __threadfence_block();
        // projection: out[o] = sum_d S[o>>3][d]*Wv2[d][o] + b2[o]
        int h0i = lane >> 3, h1i = 8 + (lane >> 3);
        float acc0 = B2v[lane], acc1 = B2v[lane + 64];
        const u32* sr0 = &sS[wv][h0i*66];
        const u32* sr1 = &sS[wv][h1i*66];
        #pragma unroll 8
        for (int j = 0; j < 64; ++j) {
            u32 us0 = sr0[j], uw0 = vw2t[j*128 + lane];
            u32 us1 = sr1[j], uw1 = vw2t[j*128 + 64 + lane];
            acc0 += lo16(us0)*lo16(uw0) + hi16(us0)*hi16(uw0);
            acc1 += lo16(us1)*lo16(uw1) + hi16(us1)*hi16(uw1);
        }
        out[(size_t)e*128 + lane] = acc0;
        out[(size_t)e*128 + 64 + lane] = acc1;
    }
}

extern "C" void kernel_launch(void* const* d_in, const int* in_sizes, int n_in,
                              void* d_out, int out_size, void* d_ws, size_t ws_size,
                              hipStream_t stream)
{
    const float* h_bond = (const float*)d_in[1];
    const float* pos    = (const float*)d_in[2];
    const float* hkW1 = (const float*)d_in[3];
    const float* hkb1 = (const float*)d_in[4];
    const float* hkg  = (const float*)d_in[5];
    const float* hkb  = (const float*)d_in[6];
    const float* hkW2 = (const float*)d_in[7];
    const float* hvW1 = (const float*)d_in[9];
    const float* hvb1 = (const float*)d_in[10];
    const float* hvg  = (const float*)d_in[11];
    const float* hvb  = (const float*)d_in[12];
    const float* hvW2 = (const float*)d_in[13];
    const float* hvb2 = (const float*)d_in[14];
    const float* hqW1 = (const float*)d_in[15];
    const float* hqb1 = (const float*)d_in[16];
    const float* hqg  = (const float*)d_in[17];
    const float* hqb  = (const float*)d_in[18];
    const float* hqW2 = (const float*)d_in[19];
    const float* hqb2 = (const float*)d_in[20];
    const int* row    = (const int*)d_in[21];
    const int* col    = (const int*)d_in[22];
    const int* idx_k  = (const int*)d_in[25];
    const int* idx_kj = (const int*)d_in[26];
    const int* idx_ji = (const int*)d_in[27];

    int E = in_sizes[21];
    int T = in_sizes[27];

    char* w = (char*)d_ws;
    size_t off = 0;
    auto carve = [&](size_t bytes) -> void* {
        void* p = w + off;
        off = (off + bytes + 255) & ~(size_t)255;
        return p;
    };
    int*  seg   = (int*) carve(((size_t)E + 1) * sizeof(int));
    bf16* qf    = (bf16*)carve((size_t)E * 128 * sizeof(bf16));
    bf16* P1k   = (bf16*)carve((size_t)E * 128 * sizeof(bf16));
    bf16* P1v   = (bf16*)carve((size_t)E * 128 * sizeof(bf16));
    u32*  kw2t  = (u32*) carve(8192 * sizeof(u32));
    u32*  vw2t  = (u32*) carve(8192 * sizeof(u32));
    int*  ctr   = (int*) carve(256);

    if (off > ws_size) {
        marker_kernel<<<(out_size + 255)/256, 256, 0, stream>>>((float*)d_out, out_size);
        return;
    }

    int gq = (E + 15)/16;
    seg_start_kernel<<<(E + 1 + 255)/256, 256, 0, stream>>>(idx_ji, T, seg, E, ctr);
    pack_w2<<<32, 256, 0, stream>>>(hkW2, hvW2, kw2t, vw2t);
    q_kernel<<<gq, 128, 0, stream>>>(hqW1, hqb1, hqg, hqb, hqW2, hqb2, h_bond, qf, E);
    p_prep<<<gq, 128, 0, stream>>>(hkW1, h_bond, pos, row, col, P1k, E);
    p_prep<<<gq, 128, 0, stream>>>(hvW1, h_bond, pos, row, col, P1v, E);
    // persistent: 4 blocks/CU x 256 CUs; waves steal edges via ctr
    fused_kernel<<<1024, 256, 0, stream>>>(kw2t, vw2t,
        hkW1, hkb1, hkg, hkb,
        hvW1, hvb1, hvg, hvb,
        hvb2, qf, P1k, P1v, pos, seg, idx_kj, idx_k, row, col, ctr, (float*)d_out, E);
}

// Round 9
// 1724.650 us; speedup vs baseline: 2.3208x; 2.3208x over previous
//
#include <hip/hip_runtime.h>
#include <hip/hip_bf16.h>
#include <math.h>

typedef __hip_bfloat16 bf16;
typedef unsigned int u32;

__device__ __forceinline__ float b2f(bf16 x){ return __bfloat162float(x); }
__device__ __forceinline__ bf16  f2b(float x){ return __float2bfloat16(x); }
__device__ __forceinline__ float lo16(u32 u){ return __uint_as_float(u << 16); }
__device__ __forceinline__ float hi16(u32 u){ return __uint_as_float(u & 0xFFFF0000u); }
// float -> bf16 bits with round-to-nearest-even
__device__ __forceinline__ u32 bfbits(float x){
    u32 u = __float_as_uint(x);
    return (u + 0x7FFFu + ((u >> 16) & 1u)) >> 16;
}

#define RSQRT8 0.35355339059327373f
#define G_STEP (10.0f/19.0f)
#define G_COEF (-0.5f/(G_STEP*G_STEP))

// butterfly layout involution: lane l holds head PERM4(l&15); PERM4 is self-inverse
__device__ __forceinline__ constexpr int PERM4(int h){
    return ((h&1)<<3) | ((h&2)<<1) | ((h&4)>>1) | ((h&8)>>3);
}

// fast atan2 for y >= 0 (result in [0, pi]); poly max err ~1.6e-6 rad
__device__ __forceinline__ float fast_atan2(float y, float x){
    float ax = fabsf(x);
    float mn = fminf(y, ax), mx = fmaxf(y, ax);
    float t = mn / fmaxf(mx, 1e-30f);
    float s = t*t;
    float p = t * (0.99997726f + s*(-0.33262347f + s*(0.19354346f +
              s*(-0.11643287f + s*(0.05265332f + s*(-0.01172120f))))));
    float r = (y > ax) ? (1.5707963267948966f - p) : p;
    r = (x < 0.f) ? (3.14159265358979323f - r) : r;
    return r;
}

// inputs are PROVEN f32

// ---------------- seg starts (idx_ji sorted) ----------------
__global__ void seg_start_kernel(const int* __restrict__ idx_ji, int T,
                                 int* __restrict__ seg, int E)
{
    int e = blockIdx.x * blockDim.x + threadIdx.x;
    if (e > E) return;
    int lo = 0, hi = T;
    while (lo < hi) { int mid = (lo + hi) >> 1; if (idx_ji[mid] < e) lo = mid + 1; else hi = mid; }
    seg[e] = lo;
}

__global__ void marker_kernel(float* out, int n){
    int i = blockIdx.x * blockDim.x + threadIdx.x;
    if (i < n) out[i] = 12345.0f;
}

// ---------------- pack W2 matrices to bf16-pair layouts (L2-resident) --------
__global__ void pack_w2(const float* __restrict__ Wk2, const float* __restrict__ Wv2,
                        u32* __restrict__ kw2t, u32* __restrict__ vw2t)
{
    int idx = blockIdx.x*256 + threadIdx.x;
    if (idx >= 8192) return;
    int c = idx >> 6, p = idx & 63;
    kw2t[idx] = bfbits(Wk2[(size_t)(2*p)*128 + c]) | (bfbits(Wk2[(size_t)(2*p+1)*128 + c]) << 16);
    int j = idx >> 7, o = idx & 127;
    vw2t[idx] = bfbits(Wv2[(size_t)(2*j)*128 + o]) | (bfbits(Wv2[(size_t)(2*j+1)*128 + o]) << 16);
}

// ---------------- q = MLP_hq(h_bond) per edge -> bf16, 4-edge batched --------
__global__ __launch_bounds__(128) void q_kernel(
    const float* __restrict__ W1, const float* __restrict__ B1,
    const float* __restrict__ G,  const float* __restrict__ Bln,
    const float* __restrict__ W2, const float* __restrict__ B2,
    const float* __restrict__ h_bond, bf16* __restrict__ qout, int E)
{
    __shared__ u32 sW[128*65];
    __shared__ float sH[16][130];
    __shared__ float sX[4][130];
    __shared__ float sRed[4][4];
    int tid = threadIdx.x; int wv = tid>>6, lane = tid&63;
    int base = blockIdx.x * 16;

    for (int idx = tid; idx < 128*128; idx += 128) {
        int i = idx >> 7, d = idx & 127;
        ((bf16*)sW)[d*130 + i] = f2b(W1[idx]);
    }
    __syncthreads();
    for (int e4 = 0; e4 < 16; e4 += 4) {
        #pragma unroll
        for (int q = 0; q < 4; ++q) {
            int e = base + e4 + q;
            sX[q][tid] = (e < E) ? h_bond[(size_t)e*128 + tid] : 0.f;
        }
        __syncthreads();
        float b1t = B1[tid];
        float ac[4] = {b1t, b1t, b1t, b1t};
        const u32* wrow = &sW[tid*65];
        #pragma unroll 4
        for (int j = 0; j < 64; ++j) {
            u32 w = wrow[j]; float wl = lo16(w), wh = hi16(w);
            #pragma unroll
            for (int q = 0; q < 4; ++q)
                ac[q] += sX[q][2*j]*wl + sX[q][2*j+1]*wh;
        }
        float s1v[4], s2v[4];
        #pragma unroll
        for (int q = 0; q < 4; ++q) { s1v[q] = ac[q]; s2v[q] = ac[q]*ac[q]; }
        #pragma unroll
        for (int m = 1; m < 64; m <<= 1) {
            #pragma unroll
            for (int q = 0; q < 4; ++q) {
                s1v[q] += __shfl_xor(s1v[q], m, 64);
                s2v[q] += __shfl_xor(s2v[q], m, 64);
            }
        }
        if (lane == 0) {
            #pragma unroll
            for (int q = 0; q < 4; ++q) { sRed[q][wv*2] = s1v[q]; sRed[q][wv*2+1] = s2v[q]; }
        }
        __syncthreads();
        float gt = G[tid], bt = Bln[tid];
        #pragma unroll
        for (int q = 0; q < 4; ++q) {
            float tot = sRed[q][0] + sRed[q][2], tot2 = sRed[q][1] + sRed[q][3];
            float mu = tot * (1.f/128.f);
            float var = fmaxf(tot2 * (1.f/128.f) - mu*mu, 0.f);
            float nv = gt * (ac[q] - mu) * rsqrtf(var + 1e-5f) + bt;
            sH[e4+q][tid] = fmaxf(nv, 0.f);
        }
        __syncthreads();
    }
    for (int idx = tid; idx < 128*128; idx += 128) {
        int i = idx >> 7, d = idx & 127;
        ((bf16*)sW)[d*130 + i] = f2b(W2[idx]);
    }
    __syncthreads();
    for (int e4 = 0; e4 < 16; e4 += 4) {
        float b2t = B2[tid];
        float ac[4] = {b2t, b2t, b2t, b2t};
        const u32* wrow = &sW[tid*65];
        #pragma unroll 4
        for (int j = 0; j < 64; ++j) {
            u32 w = wrow[j]; float wl = lo16(w), wh = hi16(w);
            #pragma unroll
            for (int q = 0; q < 4; ++q)
                ac[q] += sH[e4+q][2*j]*wl + sH[e4+q][2*j+1]*wh;
        }
        #pragma unroll
        for (int q = 0; q < 4; ++q) {
            int e = base + e4 + q;
            if (e < E) qout[(size_t)e*128 + tid] = f2b(ac[q]);
        }
    }
}

// ---------------- P1[e] = h_bond[e]@W1[0:128] + rfeat[e]@W1[128:148] -> bf16 --
// R5-proven: LDS-staged weights, 4-edge batched.
__global__ __launch_bounds__(128) void p_prep(
    const float* __restrict__ W1, const float* __restrict__ h_bond,
    const float* __restrict__ pos, const int* __restrict__ row,
    const int* __restrict__ col, bf16* __restrict__ P1, int E)
{
    __shared__ u32 sW[128*75];       // [dim][row-pair], 148 rows -> 74 pairs, stride 150 bf16
    __shared__ float sX[4][152];
    int tid = threadIdx.x;
    for (int idx = tid; idx < 148*128; idx += 128) {
        int i = idx >> 7, d = idx & 127;
        ((bf16*)sW)[d*150 + i] = f2b(W1[idx]);
    }
    __syncthreads();
    int base = blockIdx.x * 16;
    for (int e4 = 0; e4 < 16; e4 += 4) {
        #pragma unroll
        for (int q = 0; q < 4; ++q) {
            int e = base + e4 + q;
            sX[q][tid] = (e < E) ? h_bond[(size_t)e*128 + tid] : 0.f;
        }
        if (tid < 80) {
            int q = tid / 20, g = tid % 20;
            int e = base + e4 + q;
            float rf = 0.f;
            if (e < E) {
                int i0 = col[e], j0 = row[e];
                float dx = pos[(size_t)i0*3+0] - pos[(size_t)j0*3+0];
                float dy = pos[(size_t)i0*3+1] - pos[(size_t)j0*3+1];
                float dz = pos[(size_t)i0*3+2] - pos[(size_t)j0*3+2];
                float dist = sqrtf(dx*dx + dy*dy + dz*dz);
                float t = dist - (float)g * G_STEP;
                rf = __expf(G_COEF * t * t);
            }
            sX[q][128 + g] = rf;
        }
        __syncthreads();
        float acc0 = 0.f, acc1 = 0.f, acc2 = 0.f, acc3 = 0.f;
        const u32* wrow = &sW[tid*75];
        #pragma unroll 4
        for (int j = 0; j < 74; ++j) {
            u32 w = wrow[j]; float wl = lo16(w), wh = hi16(w);
            acc0 += sX[0][2*j]*wl + sX[0][2*j+1]*wh;
            acc1 += sX[1][2*j]*wl + sX[1][2*j+1]*wh;
            acc2 += sX[2][2*j]*wl + sX[2][2*j+1]*wh;
            acc3 += sX[3][2*j]*wl + sX[3][2*j+1]*wh;
        }
        int e = base + e4;
        if (e   < E) P1[(size_t)e*128     + tid] = f2b(acc0);
        if (e+1 < E) P1[(size_t)(e+1)*128 + tid] = f2b(acc1);
        if (e+2 < E) P1[(size_t)(e+2)*128 + tid] = f2b(acc2);
        if (e+3 < E) P1[(size_t)(e+3)*128 + tid] = f2b(acc3);
        __syncthreads();
    }
}

// geometry + trig identities for one triplet (suffix S)
#define GEOM(S) \
    float dt##S = ax*bx##S + ay*by##S + az*bz##S; \
    float cxx##S = ay*bz##S - az*by##S, cyy##S = az*bx##S - ax*bz##S, czz##S = ax*by##S - ay*bx##S; \
    float bb##S = cxx##S*cxx##S + cyy##S*cyy##S + czz##S*czz##S; \
    float bc##S = sqrtf(bb##S); \
    float ih##S = rsqrtf(fmaxf(dt##S*dt##S + bb##S, 1e-30f)); \
    float c1##S = dt##S * ih##S, s1##S = bc##S * ih##S; \
    float ang##S = fast_atan2(bc##S, dt##S); \
    float sh##S = sqrtf(fmaxf(0.5f*(1.f - c1##S), 0.f)); \
    float ch##S = sqrtf(fmaxf(0.5f*(1.f + c1##S), 0.f)); \
    float st3##S, ct3##S; __sincosf((1.f/3.f)*ang##S, &st3##S, &ct3##S);

// one feature: read both paths' weight pair once, 8 FMA (2 triplets x 2 paths x 2 dims)
#define FEAT(fidx, valX, valY) { \
    u32 wk_ = sWA[0][(fidx)*64 + lane]; \
    u32 wu_ = sWA[1][(fidx)*64 + lane]; \
    float wkl_ = lo16(wk_), wkh_ = hi16(wk_), wvl_ = lo16(wu_), wvh_ = hi16(wu_); \
    float fx_ = (valX), fy_ = (valY); \
    v0kX += fx_*wkl_; v1kX += fx_*wkh_; v0vX += fx_*wvl_; v1vX += fx_*wvh_; \
    v0kY += fy_*wkl_; v1kY += fy_*wkh_; v0vY += fy_*wvl_; v1vY += fy_*wvh_; }

// 7-shfl split reduction: (sum, sumsq) over 128 dims
#define LNSTATS(v0_, v1_, TOT, TOT2) { \
    float sum_ = (v0_) + (v1_), ssq_ = (v0_)*(v0_) + (v1_)*(v1_); \
    float r_ = ((lane&1) ? ssq_ : sum_) + __shfl_xor((lane&1) ? sum_ : ssq_, 1, 64); \
    r_ += __shfl_xor(r_, 2, 64);  r_ += __shfl_xor(r_, 4, 64); \
    r_ += __shfl_xor(r_, 8, 64);  r_ += __shfl_xor(r_, 16, 64); \
    r_ += __shfl_xor(r_, 32, 64); \
    float o_ = __shfl_xor(r_, 1, 64); \
    TOT = (lane&1) ? o_ : r_;  TOT2 = (lane&1) ? r_ : o_; }

#define LNAPPLY(TOT, TOT2, v0_, v1_, g_, b_, H0, H1) { \
    float mu_ = (TOT) * (1.f/128.f); \
    float var_ = fmaxf((TOT2) * (1.f/128.f) - mu_*mu_, 0.f); \
    float rs_ = rsqrtf(var_ + 1e-5f); \
    H0 = fmaxf(g_.x*((v0_)-mu_)*rs_ + b_.x, 0.f); \
    H1 = fmaxf(g_.y*((v1_)-mu_)*rs_ + b_.y, 0.f); }

// 17-shfl split-exchange butterfly: 16 reductions -> LG (head PERM4(lane&15))
#define BFLY(P, LG) { \
    float a8_[8]; \
    { int up_ = lane & 1; \
      _Pragma("unroll") \
      for (int i_ = 0; i_ < 8; ++i_) { \
        float kp_ = up_ ? P[i_+8] : P[i_]; \
        float sd_ = up_ ? P[i_]   : P[i_+8]; \
        a8_[i_] = kp_ + __shfl_xor(sd_, 1, 64); } } \
    float a4_[4]; \
    { int up_ = lane & 2; \
      _Pragma("unroll") \
      for (int i_ = 0; i_ < 4; ++i_) { \
        float kp_ = up_ ? a8_[i_+4] : a8_[i_]; \
        float sd_ = up_ ? a8_[i_]   : a8_[i_+4]; \
        a4_[i_] = kp_ + __shfl_xor(sd_, 2, 64); } } \
    float a2_[2]; \
    { int up_ = lane & 4; \
      _Pragma("unroll") \
      for (int i_ = 0; i_ < 2; ++i_) { \
        float kp_ = up_ ? a4_[i_+2] : a4_[i_]; \
        float sd_ = up_ ? a4_[i_]   : a4_[i_+2]; \
        a2_[i_] = kp_ + __shfl_xor(sd_, 4, 64); } } \
    float a1_; \
    { int up_ = lane & 8; \
      float kp_ = up_ ? a2_[1] : a2_[0]; \
      float sd_ = up_ ? a2_[0] : a2_[1]; \
      a1_ = kp_ + __shfl_xor(sd_, 8, 64); } \
    a1_ += __shfl_xor(a1_, 16, 64); \
    a1_ += __shfl_xor(a1_, 32, 64); \
    LG = a1_ * RSQRT8; }

// ---------------- fused: logits + online softmax + v-path + projection -------
// R9: ONE WAVE = ONE BLOCK = ONE EDGE. R7's 4-wave blocks retire on the
// slowest of 4 Poisson(8)-length edges -> measured 22% occupancy vs 50%
// ceiling. Per-edge blocks free their CU slot immediately; LDS/block drops
// 23040 -> 9984 B so 16 one-wave blocks/CU fit (slot ceiling unchanged,
// retire granularity 4x finer). R8's persistent-loop alternative spilled
// (128 VGPR + 3.2GB scratch) - loop-carried live set too big. Also: gaussian
// rf computed once per edge for both k/v paths (-20 expf/edge, from R8).
__global__ __launch_bounds__(64)
void fused_kernel(
    const u32* __restrict__ kw2t, const u32* __restrict__ vw2t,
    const float* __restrict__ Wk1, const float* __restrict__ Bk1,
    const float* __restrict__ Gkg, const float* __restrict__ Bkln,
    const float* __restrict__ Wv1, const float* __restrict__ Bv1,
    const float* __restrict__ Gvg, const float* __restrict__ Bvln,
    const float* __restrict__ B2v,
    const bf16* __restrict__ qf, const bf16* __restrict__ P1k, const bf16* __restrict__ P1v,
    const float* __restrict__ pos, const int* __restrict__ seg,
    const int* __restrict__ idx_kj, const int* __restrict__ idx_k,
    const int* __restrict__ row, const int* __restrict__ col,
    float* __restrict__ out, int E)
{
    __shared__ u32 sS[16*66];        // epilogue staging; loop-time overlay holds Gk (4224 B)
    __shared__ u32 sWA[2][11*64];    // deduped angular weight pairs: [path][f][lane] (5632 B)
    __shared__ float2 sEx[16];       // (exX, exY) per head (128 B)
    int lane = threadIdx.x & 63;

    int e = __builtin_amdgcn_readfirstlane(blockIdx.x);
    if (e >= E) return;
    int s0 = __builtin_amdgcn_readfirstlane(seg[e]);
    int s1 = __builtin_amdgcn_readfirstlane(seg[e+1]);
    if (s1 <= s0) { out[(size_t)e*128 + lane] = 0.f; out[(size_t)e*128 + 64 + lane] = 0.f; return; }

    // wave-cooperative populate of sWA (both paths by the single wave).
    // Feature order: {ang, s1, s2, s3, sh, st3, c1, c2, c3, ch, ct3};
    // s1 at {1,4}, c1 at {7,10} folded.
    #pragma unroll
    for (int path = 0; path < 2; ++path) {
        const float* W1full = path ? Wv1 : Wk1;
        const float2* wap = (const float2*)(W1full + (size_t)168*128);
        float2 w0  = wap[ 0*64 + lane];
        float2 w1  = wap[ 1*64 + lane];
        float2 w2  = wap[ 2*64 + lane];
        float2 w3  = wap[ 3*64 + lane];
        float2 w4  = wap[ 4*64 + lane];
        float2 w5  = wap[ 5*64 + lane];
        float2 w6  = wap[ 6*64 + lane];
        float2 w7  = wap[ 7*64 + lane];
        float2 w8  = wap[ 8*64 + lane];
        float2 w9  = wap[ 9*64 + lane];
        float2 w10 = wap[10*64 + lane];
        float2 w11 = wap[11*64 + lane];
        float2 w12 = wap[12*64 + lane];
        u32* dst = &sWA[path][0];
        dst[ 0*64 + lane] = bfbits(w0.x)       | (bfbits(w0.y)       << 16);
        dst[ 1*64 + lane] = bfbits(w1.x+w4.x)  | (bfbits(w1.y+w4.y)  << 16);
        dst[ 2*64 + lane] = bfbits(w2.x)       | (bfbits(w2.y)       << 16);
        dst[ 3*64 + lane] = bfbits(w3.x)       | (bfbits(w3.y)       << 16);
        dst[ 4*64 + lane] = bfbits(w5.x)       | (bfbits(w5.y)       << 16);
        dst[ 5*64 + lane] = bfbits(w6.x)       | (bfbits(w6.y)       << 16);
        dst[ 6*64 + lane] = bfbits(w7.x+w10.x) | (bfbits(w7.y+w10.y) << 16);
        dst[ 7*64 + lane] = bfbits(w8.x)       | (bfbits(w8.y)       << 16);
        dst[ 8*64 + lane] = bfbits(w9.x)       | (bfbits(w9.y)       << 16);
        dst[ 9*64 + lane] = bfbits(w11.x)      | (bfbits(w11.y)      << 16);
        dst[10*64 + lane] = bfbits(w12.x)      | (bfbits(w12.y)      << 16);
    }
    __syncthreads();                 // single wave: compiles to waitcnt (cheap)

    float2 b1k = ((const float2*)Bk1)[lane];
    float2 gk  = ((const float2*)Gkg)[lane];
    float2 bk  = ((const float2*)Bkln)[lane];
    float2 b1v = ((const float2*)Bv1)[lane];
    float2 gv  = ((const float2*)Gvg)[lane];
    float2 bv  = ((const float2*)Bvln)[lane];

    int i0 = __builtin_amdgcn_readfirstlane(col[e]);
    int j0 = __builtin_amdgcn_readfirstlane(row[e]);
    float pix = pos[(size_t)i0*3+0], piy = pos[(size_t)i0*3+1], piz = pos[(size_t)i0*3+2];
    float pjx = pos[(size_t)j0*3+0], pjy = pos[(size_t)j0*3+1], pjz = pos[(size_t)j0*3+2];
    float dxx = pix-pjx, dyy = piy-pjy, dzz = piz-pjz;
    float dist = sqrtf(dxx*dxx + dyy*dyy + dzz*dzz);

    // P2 pre-act for BOTH paths with shared rf (one expf per gaussian)
    float P2ak = b1k.x, P2bk = b1k.y, P2av = b1v.x, P2bv = b1v.y;
    {
        const float2* wbk = (const float2*)(Wk1 + (size_t)148*128);
        const float2* wbv = (const float2*)(Wv1 + (size_t)148*128);
        for (int g2 = 0; g2 < 20; ++g2) {
            float tg = dist - (float)g2 * G_STEP;
            float rf = __expf(G_COEF * tg * tg);
            float2 wk = wbk[g2*64 + lane];
            float2 wu = wbv[g2*64 + lane];
            P2ak += rf * wk.x; P2bk += rf * wk.y;
            P2av += rf * wu.x; P2bv += rf * wu.y;
        }
    }

    // Gk[h] packed bf16 pair -> LDS (overlay on sS; loop-only lifetime)
    u32* sGkw = &sS[0];
    {
        const u32* qrow = (const u32*)(qf + (size_t)e*128);
        #pragma unroll
        for (int h = 0; h < 16; ++h) {
            float g0 = 0.f, g1 = 0.f;
            #pragma unroll
            for (int j = 0; j < 4; ++j) {
                u32 qp = qrow[h*4 + j];
                float ql = lo16(qp), qh = hi16(qp);
                u32 w0 = kw2t[(h*8 + 2*j)*64 + lane];
                u32 w1 = kw2t[(h*8 + 2*j + 1)*64 + lane];
                g0 += ql*lo16(w0) + qh*lo16(w1);
                g1 += ql*hi16(w0) + qh*hi16(w1);
            }
            sGkw[h*64 + lane] = bfbits(g0) | (bfbits(g1) << 16);
        }
    }

    float S0[16], S1[16];
    #pragma unroll
    for (int h = 0; h < 16; ++h) { S0[h] = 0.f; S1[h] = 0.f; }
    float m = -1e30f, sden = 0.f;

    const u32* p1ku = (const u32*)P1k;
    const u32* p1vu = (const u32*)P1v;
    float ax = pjx-pix, ay = pjy-piy, az = pjz-piz;
    int perm = ((lane&1)<<3) | ((lane&2)<<1) | ((lane&4)>>1) | ((lane&8)>>3);

    // 2-ahead prefetch state for triplet pair (X, Y)
    int tB0 = (s0+1 < s1) ? s0+1 : s0;
    int kjX = __builtin_amdgcn_readfirstlane(idx_kj[s0]);
    int knX = __builtin_amdgcn_readfirstlane(idx_k[s0]);
    int kjY = __builtin_amdgcn_readfirstlane(idx_kj[tB0]);
    int knY = __builtin_amdgcn_readfirstlane(idx_k[tB0]);
    u32 fppkX = p1ku[(size_t)kjX*64 + lane], fppvX = p1vu[(size_t)kjX*64 + lane];
    u32 fppkY = p1ku[(size_t)kjY*64 + lane], fppvY = p1vu[(size_t)kjY*64 + lane];
    float fpkxX = pos[(size_t)knX*3+0], fpkyX = pos[(size_t)knX*3+1], fpkzX = pos[(size_t)knX*3+2];
    float fpkxY = pos[(size_t)knY*3+0], fpkyY = pos[(size_t)knY*3+1], fpkzY = pos[(size_t)knY*3+2];

    for (int t = s0; t < s1; t += 2) {
        const bool twoY = (t+1 < s1);
        // consume prefetched
        u32 ppkX = fppkX, ppvX = fppvX, ppkY = fppkY, ppvY = fppvY;
        float bxX = fpkxX-pix, byX = fpkyX-piy, bzX = fpkzX-piz;
        float bxY = fpkxY-pix, byY = fpkyY-piy, bzY = fpkzY-piz;
        // issue next-pair prefetch (clamped; duplicates harmless)
        int tn0 = (t+2 < s1) ? t+2 : s1-1;
        int tn1 = (t+3 < s1) ? t+3 : s1-1;
        kjX = __builtin_amdgcn_readfirstlane(idx_kj[tn0]);
        knX = __builtin_amdgcn_readfirstlane(idx_k[tn0]);
        kjY = __builtin_amdgcn_readfirstlane(idx_kj[tn1]);
        knY = __builtin_amdgcn_readfirstlane(idx_k[tn1]);
        fppkX = p1ku[(size_t)kjX*64 + lane]; fppvX = p1vu[(size_t)kjX*64 + lane];
        fppkY = p1ku[(size_t)kjY*64 + lane]; fppvY = p1vu[(size_t)kjY*64 + lane];
        fpkxX = pos[(size_t)knX*3+0]; fpkyX = pos[(size_t)knX*3+1]; fpkzX = pos[(size_t)knX*3+2];
        fpkxY = pos[(size_t)knY*3+0]; fpkyY = pos[(size_t)knY*3+1]; fpkzY = pos[(size_t)knY*3+2];

        GEOM(X);
        GEOM(Y);

        // pre-activations: k/v paths x triplets X/Y
        float v0kX = P2ak + lo16(ppkX), v1kX = P2bk + hi16(ppkX);
        float v0vX = P2av + lo16(ppvX), v1vX = P2bv + hi16(ppvX);
        float v0kY = P2ak + lo16(ppkY), v1kY = P2bk + hi16(ppkY);
        float v0vY = P2av + lo16(ppvY), v1vY = P2bv + hi16(ppvY);

        FEAT(0,  angX, angY);
        FEAT(1,  s1X,  s1Y);
        FEAT(2,  2.f*s1X*c1X, 2.f*s1Y*c1Y);
        FEAT(3,  s1X*(3.f - 4.f*s1X*s1X), s1Y*(3.f - 4.f*s1Y*s1Y));
        FEAT(4,  shX,  shY);
        FEAT(5,  st3X, st3Y);
        FEAT(6,  c1X,  c1Y);
        FEAT(7,  1.f - 2.f*s1X*s1X, 1.f - 2.f*s1Y*s1Y);
        FEAT(8,  c1X*(4.f*c1X*c1X - 3.f), c1Y*(4.f*c1Y*c1Y - 3.f));
        FEAT(9,  chX,  chY);
        FEAT(10, ct3X, ct3Y);

        // 4 independent LN chains (compiler interleaves)
        float totKX, tot2KX, totVX, tot2VX, totKY, tot2KY, totVY, tot2VY;
        LNSTATS(v0kX, v1kX, totKX, tot2KX);
        LNSTATS(v0vX, v1vX, totVX, tot2VX);
        LNSTATS(v0kY, v1kY, totKY, tot2KY);
        LNSTATS(v0vY, v1vY, totVY, tot2VY);
        float h0kX, h1kX, h0vX, h1vX, h0kY, h1kY, h0vY, h1vY;
        LNAPPLY(totKX, tot2KX, v0kX, v1kX, gk, bk, h0kX, h1kX);
        LNAPPLY(totVX, tot2VX, v0vX, v1vX, gv, bv, h0vX, h1vX);
        LNAPPLY(totKY, tot2KY, v0kY, v1kY, gk, bk, h0kY, h1kY);
        LNAPPLY(totVY, tot2VY, v0vY, v1vY, gv, bv, h0vY, h1vY);

        // per-head logit partials (Gk from LDS, read once for X and Y)
        float pX[16], pY[16];
        #pragma unroll
        for (int h = 0; h < 16; ++h) {
            u32 g = sGkw[h*64 + lane];
            float gl = lo16(g), gh = hi16(g);
            pX[h] = h0kX*gl + h1kX*gh;
            pY[h] = h0kY*gl + h1kY*gh;
        }
        float lgX, lgY;
        BFLY(pX, lgX);
        BFLY(pY, lgY);

        // online softmax (pair): one deferred-max check covers both logits
        float mx = fmaxf(lgX, lgY);
        if (__any(mx > m + 8.f)) {
            float nm = fmaxf(m, mx);
            float fac = __expf(m - nm);
            sden *= fac; m = nm;
            #pragma unroll
            for (int h = 0; h < 16; ++h) {
                float fh = __shfl(fac, PERM4(h), 64);
                S0[h] *= fh; S1[h] *= fh;
            }
        }
        float exX = __expf(lgX - m);
        float exY = twoY ? __expf(lgY - m) : 0.f;   // masked tail: no double count
        sden += exX + exY;
        // broadcast via LDS (replaces 16 ds_bpermute)
        if (lane < 16) sEx[perm] = make_float2(exX, exY);
        #pragma unroll
        for (int h = 0; h < 16; ++h) {
            float2 eh = sEx[h];
            S0[h] += eh.x*h0vX + eh.y*h0vY;
            S1[h] += eh.x*h1vX + eh.y*h1vY;
        }
    }

    // normalize by softmax denominator while staging S as bf16 pairs
    float inv = 1.f / sden;
    #pragma unroll
    for (int h = 0; h < 16; ++h) {
        float sc = __shfl(inv, PERM4(h), 64);
        sS[h*66 + lane] = bfbits(S0[h]*sc) | (bfbits(S1[h]*sc) << 16);
    }
    __threadfence_block();
    // projection: out[o] = sum_d S[o>>3][d]*Wv2[d][o] + b2[o]
    int h0i = lane >> 3, h1i = 8 + (lane >> 3);
    float acc0 = B2v[lane], acc1 = B2v[lane + 64];
    const u32* sr0 = &sS[h0i*66];
    const u32* sr1 = &sS[h1i*66];
    #pragma unroll 8
    for (int j = 0; j < 64; ++j) {
        u32 us0 = sr0[j], uw0 = vw2t[j*128 + lane];
        u32 us1 = sr1[j], uw1 = vw2t[j*128 + 64 + lane];
        acc0 += lo16(us0)*lo16(uw0) + hi16(us0)*hi16(uw0);
        acc1 += lo16(us1)*lo16(uw1) + hi16(us1)*hi16(uw1);
    }
    out[(size_t)e*128 + lane] = acc0;
    out[(size_t)e*128 + 64 + lane] = acc1;
}

extern "C" void kernel_launch(void* const* d_in, const int* in_sizes, int n_in,
                              void* d_out, int out_size, void* d_ws, size_t ws_size,
                              hipStream_t stream)
{
    const float* h_bond = (const float*)d_in[1];
    const float* pos    = (const float*)d_in[2];
    const float* hkW1 = (const float*)d_in[3];
    const float* hkb1 = (const float*)d_in[4];
    const float* hkg  = (const float*)d_in[5];
    const float* hkb  = (const float*)d_in[6];
    const float* hkW2 = (const float*)d_in[7];
    const float* hvW1 = (const float*)d_in[9];
    const float* hvb1 = (const float*)d_in[10];
    const float* hvg  = (const float*)d_in[11];
    const float* hvb  = (const float*)d_in[12];
    const float* hvW2 = (const float*)d_in[13];
    const float* hvb2 = (const float*)d_in[14];
    const float* hqW1 = (const float*)d_in[15];
    const float* hqb1 = (const float*)d_in[16];
    const float* hqg  = (const float*)d_in[17];
    const float* hqb  = (const float*)d_in[18];
    const float* hqW2 = (const float*)d_in[19];
    const float* hqb2 = (const float*)d_in[20];
    const int* row    = (const int*)d_in[21];
    const int* col    = (const int*)d_in[22];
    const int* idx_k  = (const int*)d_in[25];
    const int* idx_kj = (const int*)d_in[26];
    const int* idx_ji = (const int*)d_in[27];

    int E = in_sizes[21];
    int T = in_sizes[27];

    char* w = (char*)d_ws;
    size_t off = 0;
    auto carve = [&](size_t bytes) -> void* {
        void* p = w + off;
        off = (off + bytes + 255) & ~(size_t)255;
        return p;
    };
    int*  seg   = (int*) carve(((size_t)E + 1) * sizeof(int));
    bf16* qf    = (bf16*)carve((size_t)E * 128 * sizeof(bf16));
    bf16* P1k   = (bf16*)carve((size_t)E * 128 * sizeof(bf16));
    bf16* P1v   = (bf16*)carve((size_t)E * 128 * sizeof(bf16));
    u32*  kw2t  = (u32*) carve(8192 * sizeof(u32));
    u32*  vw2t  = (u32*) carve(8192 * sizeof(u32));

    if (off > ws_size) {
        marker_kernel<<<(out_size + 255)/256, 256, 0, stream>>>((float*)d_out, out_size);
        return;
    }

    int gq = (E + 15)/16;
    seg_start_kernel<<<(E + 1 + 255)/256, 256, 0, stream>>>(idx_ji, T, seg, E);
    pack_w2<<<32, 256, 0, stream>>>(hkW2, hvW2, kw2t, vw2t);
    q_kernel<<<gq, 128, 0, stream>>>(hqW1, hqb1, hqg, hqb, hqW2, hqb2, h_bond, qf, E);
    p_prep<<<gq, 128, 0, stream>>>(hkW1, h_bond, pos, row, col, P1k, E);
    p_prep<<<gq, 128, 0, stream>>>(hvW1, h_bond, pos, row, col, P1v, E);
    // one wave = one block = one edge: fine-grained retire, 16 blocks/CU
    fused_kernel<<<E, 64, 0, stream>>>(kw2t, vw2t,
        hkW1, hkb1, hkg, hkb,
        hvW1, hvb1, hvg, hvb,
        hvb2, qf, P1k, P1v, pos, seg, idx_kj, idx_k, row, col, (float*)d_out, E);
}

// Round 10
// 1685.878 us; speedup vs baseline: 2.3742x; 1.0230x over previous
//
#include <hip/hip_runtime.h>
#include <hip/hip_bf16.h>
#include <math.h>

typedef __hip_bfloat16 bf16;
typedef unsigned int u32;

__device__ __forceinline__ float b2f(bf16 x){ return __bfloat162float(x); }
__device__ __forceinline__ bf16  f2b(float x){ return __float2bfloat16(x); }
__device__ __forceinline__ float lo16(u32 u){ return __uint_as_float(u << 16); }
__device__ __forceinline__ float hi16(u32 u){ return __uint_as_float(u & 0xFFFF0000u); }
// float -> bf16 bits with round-to-nearest-even
__device__ __forceinline__ u32 bfbits(float x){
    u32 u = __float_as_uint(x);
    return (u + 0x7FFFu + ((u >> 16) & 1u)) >> 16;
}

#define RSQRT8 0.35355339059327373f
#define G_STEP (10.0f/19.0f)
#define G_COEF (-0.5f/(G_STEP*G_STEP))

// butterfly layout involution: lane l holds head PERM4(l&15); PERM4 is self-inverse
__device__ __forceinline__ constexpr int PERM4(int h){
    return ((h&1)<<3) | ((h&2)<<1) | ((h&4)>>1) | ((h&8)>>3);
}

// fast atan2 for y >= 0 (result in [0, pi]); poly max err ~1.6e-6 rad
__device__ __forceinline__ float fast_atan2(float y, float x){
    float ax = fabsf(x);
    float mn = fminf(y, ax), mx = fmaxf(y, ax);
    float t = mn / fmaxf(mx, 1e-30f);
    float s = t*t;
    float p = t * (0.99997726f + s*(-0.33262347f + s*(0.19354346f +
              s*(-0.11643287f + s*(0.05265332f + s*(-0.01172120f))))));
    float r = (y > ax) ? (1.5707963267948966f - p) : p;
    r = (x < 0.f) ? (3.14159265358979323f - r) : r;
    return r;
}

// inputs are PROVEN f32

// ---------------- seg starts (idx_ji sorted) ----------------
__global__ void seg_start_kernel(const int* __restrict__ idx_ji, int T,
                                 int* __restrict__ seg, int E)
{
    int e = blockIdx.x * blockDim.x + threadIdx.x;
    if (e > E) return;
    int lo = 0, hi = T;
    while (lo < hi) { int mid = (lo + hi) >> 1; if (idx_ji[mid] < e) lo = mid + 1; else hi = mid; }
    seg[e] = lo;
}

__global__ void marker_kernel(float* out, int n){
    int i = blockIdx.x * blockDim.x + threadIdx.x;
    if (i < n) out[i] = 12345.0f;
}

// ---------------- pack W2 matrices to bf16-pair layouts (L2-resident) --------
__global__ void pack_w2(const float* __restrict__ Wk2, const float* __restrict__ Wv2,
                        u32* __restrict__ kw2t, u32* __restrict__ vw2t)
{
    int idx = blockIdx.x*256 + threadIdx.x;
    if (idx >= 8192) return;
    int c = idx >> 6, p = idx & 63;
    kw2t[idx] = bfbits(Wk2[(size_t)(2*p)*128 + c]) | (bfbits(Wk2[(size_t)(2*p+1)*128 + c]) << 16);
    int j = idx >> 7, o = idx & 127;
    vw2t[idx] = bfbits(Wv2[(size_t)(2*j)*128 + o]) | (bfbits(Wv2[(size_t)(2*j+1)*128 + o]) << 16);
}

// ---------------- q = MLP_hq(h_bond) per edge -> bf16, 4-edge batched --------
__global__ __launch_bounds__(128) void q_kernel(
    const float* __restrict__ W1, const float* __restrict__ B1,
    const float* __restrict__ G,  const float* __restrict__ Bln,
    const float* __restrict__ W2, const float* __restrict__ B2,
    const float* __restrict__ h_bond, bf16* __restrict__ qout, int E)
{
    __shared__ u32 sW[128*65];
    __shared__ float sH[16][130];
    __shared__ float sX[4][130];
    __shared__ float sRed[4][4];
    int tid = threadIdx.x; int wv = tid>>6, lane = tid&63;
    int base = blockIdx.x * 16;

    for (int idx = tid; idx < 128*128; idx += 128) {
        int i = idx >> 7, d = idx & 127;
        ((bf16*)sW)[d*130 + i] = f2b(W1[idx]);
    }
    __syncthreads();
    for (int e4 = 0; e4 < 16; e4 += 4) {
        #pragma unroll
        for (int q = 0; q < 4; ++q) {
            int e = base + e4 + q;
            sX[q][tid] = (e < E) ? h_bond[(size_t)e*128 + tid] : 0.f;
        }
        __syncthreads();
        float b1t = B1[tid];
        float ac[4] = {b1t, b1t, b1t, b1t};
        const u32* wrow = &sW[tid*65];
        #pragma unroll 4
        for (int j = 0; j < 64; ++j) {
            u32 w = wrow[j]; float wl = lo16(w), wh = hi16(w);
            #pragma unroll
            for (int q = 0; q < 4; ++q)
                ac[q] += sX[q][2*j]*wl + sX[q][2*j+1]*wh;
        }
        float s1v[4], s2v[4];
        #pragma unroll
        for (int q = 0; q < 4; ++q) { s1v[q] = ac[q]; s2v[q] = ac[q]*ac[q]; }
        #pragma unroll
        for (int m = 1; m < 64; m <<= 1) {
            #pragma unroll
            for (int q = 0; q < 4; ++q) {
                s1v[q] += __shfl_xor(s1v[q], m, 64);
                s2v[q] += __shfl_xor(s2v[q], m, 64);
            }
        }
        if (lane == 0) {
            #pragma unroll
            for (int q = 0; q < 4; ++q) { sRed[q][wv*2] = s1v[q]; sRed[q][wv*2+1] = s2v[q]; }
        }
        __syncthreads();
        float gt = G[tid], bt = Bln[tid];
        #pragma unroll
        for (int q = 0; q < 4; ++q) {
            float tot = sRed[q][0] + sRed[q][2], tot2 = sRed[q][1] + sRed[q][3];
            float mu = tot * (1.f/128.f);
            float var = fmaxf(tot2 * (1.f/128.f) - mu*mu, 0.f);
            float nv = gt * (ac[q] - mu) * rsqrtf(var + 1e-5f) + bt;
            sH[e4+q][tid] = fmaxf(nv, 0.f);
        }
        __syncthreads();
    }
    for (int idx = tid; idx < 128*128; idx += 128) {
        int i = idx >> 7, d = idx & 127;
        ((bf16*)sW)[d*130 + i] = f2b(W2[idx]);
    }
    __syncthreads();
    for (int e4 = 0; e4 < 16; e4 += 4) {
        float b2t = B2[tid];
        float ac[4] = {b2t, b2t, b2t, b2t};
        const u32* wrow = &sW[tid*65];
        #pragma unroll 4
        for (int j = 0; j < 64; ++j) {
            u32 w = wrow[j]; float wl = lo16(w), wh = hi16(w);
            #pragma unroll
            for (int q = 0; q < 4; ++q)
                ac[q] += sH[e4+q][2*j]*wl + sH[e4+q][2*j+1]*wh;
        }
        #pragma unroll
        for (int q = 0; q < 4; ++q) {
            int e = base + e4 + q;
            if (e < E) qout[(size_t)e*128 + tid] = f2b(ac[q]);
        }
    }
}

// ---------------- P1k AND P1v in one pass -----------------------------------
// R10: both weight matrices in LDS (76.8KB -> 2 blocks/CU); h_bond staged ONCE
// for both matmuls; rfeat computed once; inner loop reads each x pair once and
// feeds both accumulator sets (6 LDS ops/iter vs 10 across two kernels).
__global__ __launch_bounds__(128) void p_prep2(
    const float* __restrict__ Wk1, const float* __restrict__ Wv1,
    const float* __restrict__ h_bond, const float* __restrict__ pos,
    const int* __restrict__ row, const int* __restrict__ col,
    bf16* __restrict__ P1k, bf16* __restrict__ P1v, int E)
{
    __shared__ u32 sWk[128*75];      // [dim][row-pair], stride 150 bf16
    __shared__ u32 sWv[128*75];
    __shared__ float sX[4][152];
    int tid = threadIdx.x;
    for (int idx = tid; idx < 148*128; idx += 128) {
        int i = idx >> 7, d = idx & 127;
        ((bf16*)sWk)[d*150 + i] = f2b(Wk1[idx]);
        ((bf16*)sWv)[d*150 + i] = f2b(Wv1[idx]);
    }
    __syncthreads();
    int base = blockIdx.x * 16;
    for (int e4 = 0; e4 < 16; e4 += 4) {
        #pragma unroll
        for (int q = 0; q < 4; ++q) {
            int e = base + e4 + q;
            sX[q][tid] = (e < E) ? h_bond[(size_t)e*128 + tid] : 0.f;
        }
        if (tid < 80) {
            int q = tid / 20, g = tid % 20;
            int e = base + e4 + q;
            float rf = 0.f;
            if (e < E) {
                int i0 = col[e], j0 = row[e];
                float dx = pos[(size_t)i0*3+0] - pos[(size_t)j0*3+0];
                float dy = pos[(size_t)i0*3+1] - pos[(size_t)j0*3+1];
                float dz = pos[(size_t)i0*3+2] - pos[(size_t)j0*3+2];
                float dist = sqrtf(dx*dx + dy*dy + dz*dz);
                float t = dist - (float)g * G_STEP;
                rf = __expf(G_COEF * t * t);
            }
            sX[q][128 + g] = rf;
        }
        __syncthreads();
        float ak0 = 0.f, ak1 = 0.f, ak2 = 0.f, ak3 = 0.f;
        float av0 = 0.f, av1 = 0.f, av2 = 0.f, av3 = 0.f;
        const u32* wkr = &sWk[tid*75];
        const u32* wvr = &sWv[tid*75];
        #pragma unroll 2
        for (int j = 0; j < 74; ++j) {
            u32 wk = wkr[j], wu = wvr[j];
            float wkl = lo16(wk), wkh = hi16(wk);
            float wvl = lo16(wu), wvh = hi16(wu);
            float2 x0 = ((const float2*)sX[0])[j];
            float2 x1 = ((const float2*)sX[1])[j];
            float2 x2 = ((const float2*)sX[2])[j];
            float2 x3 = ((const float2*)sX[3])[j];
            ak0 += x0.x*wkl + x0.y*wkh;  av0 += x0.x*wvl + x0.y*wvh;
            ak1 += x1.x*wkl + x1.y*wkh;  av1 += x1.x*wvl + x1.y*wvh;
            ak2 += x2.x*wkl + x2.y*wkh;  av2 += x2.x*wvl + x2.y*wvh;
            ak3 += x3.x*wkl + x3.y*wkh;  av3 += x3.x*wvl + x3.y*wvh;
        }
        int e = base + e4;
        if (e   < E) { P1k[(size_t)e*128     + tid] = f2b(ak0); P1v[(size_t)e*128     + tid] = f2b(av0); }
        if (e+1 < E) { P1k[(size_t)(e+1)*128 + tid] = f2b(ak1); P1v[(size_t)(e+1)*128 + tid] = f2b(av1); }
        if (e+2 < E) { P1k[(size_t)(e+2)*128 + tid] = f2b(ak2); P1v[(size_t)(e+2)*128 + tid] = f2b(av2); }
        if (e+3 < E) { P1k[(size_t)(e+3)*128 + tid] = f2b(ak3); P1v[(size_t)(e+3)*128 + tid] = f2b(av3); }
        __syncthreads();
    }
}

// geometry + trig identities for one triplet (suffix S)
#define GEOM(S) \
    float dt##S = ax*bx##S + ay*by##S + az*bz##S; \
    float cxx##S = ay*bz##S - az*by##S, cyy##S = az*bx##S - ax*bz##S, czz##S = ax*by##S - ay*bx##S; \
    float bb##S = cxx##S*cxx##S + cyy##S*cyy##S + czz##S*czz##S; \
    float bc##S = sqrtf(bb##S); \
    float ih##S = rsqrtf(fmaxf(dt##S*dt##S + bb##S, 1e-30f)); \
    float c1##S = dt##S * ih##S, s1##S = bc##S * ih##S; \
    float ang##S = fast_atan2(bc##S, dt##S); \
    float sh##S = sqrtf(fmaxf(0.5f*(1.f - c1##S), 0.f)); \
    float ch##S = sqrtf(fmaxf(0.5f*(1.f + c1##S), 0.f)); \
    float st3##S, ct3##S; __sincosf((1.f/3.f)*ang##S, &st3##S, &ct3##S);

// one feature: read both paths' weight pair once, 8 FMA (2 triplets x 2 paths x 2 dims)
#define FEAT(fidx, valX, valY) { \
    u32 wk_ = sWA[0][(fidx)*64 + lane]; \
    u32 wu_ = sWA[1][(fidx)*64 + lane]; \
    float wkl_ = lo16(wk_), wkh_ = hi16(wk_), wvl_ = lo16(wu_), wvh_ = hi16(wu_); \
    float fx_ = (valX), fy_ = (valY); \
    v0kX += fx_*wkl_; v1kX += fx_*wkh_; v0vX += fx_*wvl_; v1vX += fx_*wvh_; \
    v0kY += fy_*wkl_; v1kY += fy_*wkh_; v0vY += fy_*wvl_; v1vY += fy_*wvh_; }

// 7-shfl split reduction: (sum, sumsq) over 128 dims
#define LNSTATS(v0_, v1_, TOT, TOT2) { \
    float sum_ = (v0_) + (v1_), ssq_ = (v0_)*(v0_) + (v1_)*(v1_); \
    float r_ = ((lane&1) ? ssq_ : sum_) + __shfl_xor((lane&1) ? sum_ : ssq_, 1, 64); \
    r_ += __shfl_xor(r_, 2, 64);  r_ += __shfl_xor(r_, 4, 64); \
    r_ += __shfl_xor(r_, 8, 64);  r_ += __shfl_xor(r_, 16, 64); \
    r_ += __shfl_xor(r_, 32, 64); \
    float o_ = __shfl_xor(r_, 1, 64); \
    TOT = (lane&1) ? o_ : r_;  TOT2 = (lane&1) ? r_ : o_; }

#define LNAPPLY(TOT, TOT2, v0_, v1_, g_, b_, H0, H1) { \
    float mu_ = (TOT) * (1.f/128.f); \
    float var_ = fmaxf((TOT2) * (1.f/128.f) - mu_*mu_, 0.f); \
    float rs_ = rsqrtf(var_ + 1e-5f); \
    H0 = fmaxf(g_.x*((v0_)-mu_)*rs_ + b_.x, 0.f); \
    H1 = fmaxf(g_.y*((v1_)-mu_)*rs_ + b_.y, 0.f); }

// 17-shfl split-exchange butterfly: 16 reductions -> LG (head PERM4(lane&15))
#define BFLY(P, LG) { \
    float a8_[8]; \
    { int up_ = lane & 1; \
      _Pragma("unroll") \
      for (int i_ = 0; i_ < 8; ++i_) { \
        float kp_ = up_ ? P[i_+8] : P[i_]; \
        float sd_ = up_ ? P[i_]   : P[i_+8]; \
        a8_[i_] = kp_ + __shfl_xor(sd_, 1, 64); } } \
    float a4_[4]; \
    { int up_ = lane & 2; \
      _Pragma("unroll") \
      for (int i_ = 0; i_ < 4; ++i_) { \
        float kp_ = up_ ? a8_[i_+4] : a8_[i_]; \
        float sd_ = up_ ? a8_[i_]   : a8_[i_+4]; \
        a4_[i_] = kp_ + __shfl_xor(sd_, 2, 64); } } \
    float a2_[2]; \
    { int up_ = lane & 4; \
      _Pragma("unroll") \
      for (int i_ = 0; i_ < 2; ++i_) { \
        float kp_ = up_ ? a4_[i_+2] : a4_[i_]; \
        float sd_ = up_ ? a4_[i_]   : a4_[i_+2]; \
        a2_[i_] = kp_ + __shfl_xor(sd_, 4, 64); } } \
    float a1_; \
    { int up_ = lane & 8; \
      float kp_ = up_ ? a2_[1] : a2_[0]; \
      float sd_ = up_ ? a2_[0] : a2_[1]; \
      a1_ = kp_ + __shfl_xor(sd_, 8, 64); } \
    a1_ += __shfl_xor(a1_, 16, 64); \
    a1_ += __shfl_xor(a1_, 32, 64); \
    LG = a1_ * RSQRT8; }

// ---------------- fused: logits + online softmax + v-path + projection -------
// R10: REVERT to R7's proven 4-wave structure (best measured: 953us, VALUBusy
// 79%, zero spill). R9's 1-wave/block test refuted the retire-granularity
// theory (occupancy invariant ~22-23%) and cost +130MB FETCH from 4x sWA
// restaging. Kept from R9: single gaussian loop feeds both k/v paths.
__global__ __launch_bounds__(256, 2)
void fused_kernel(
    const u32* __restrict__ kw2t, const u32* __restrict__ vw2t,
    const float* __restrict__ Wk1, const float* __restrict__ Bk1,
    const float* __restrict__ Gkg, const float* __restrict__ Bkln,
    const float* __restrict__ Wv1, const float* __restrict__ Bv1,
    const float* __restrict__ Gvg, const float* __restrict__ Bvln,
    const float* __restrict__ B2v,
    const bf16* __restrict__ qf, const bf16* __restrict__ P1k, const bf16* __restrict__ P1v,
    const float* __restrict__ pos, const int* __restrict__ seg,
    const int* __restrict__ idx_kj, const int* __restrict__ idx_k,
    const int* __restrict__ row, const int* __restrict__ col,
    float* __restrict__ out, int E)
{
    __shared__ u32 sS[4][16*66];     // epilogue staging; loop-time overlay holds Gk
    __shared__ u32 sWA[2][11*64];    // deduped angular weight pairs: [path][f][lane]
    __shared__ float2 sEx[4][16];    // per-wave (exX, exY) per head
    int tid = threadIdx.x, lane = tid & 63, wv = tid >> 6;

    // block-cooperative populate of sWA. Feature order:
    // {ang, s1, s2, s3, sh, st3, c1, c2, c3, ch, ct3}; s1 at {1,4}, c1 at {7,10} folded.
    if (tid < 128) {
        int path = tid >> 6, l = tid & 63;
        const float* W1full = path ? Wv1 : Wk1;
        const float2* wap = (const float2*)(W1full + (size_t)168*128);
        float2 w0  = wap[ 0*64 + l];
        float2 w1  = wap[ 1*64 + l];
        float2 w2  = wap[ 2*64 + l];
        float2 w3  = wap[ 3*64 + l];
        float2 w4  = wap[ 4*64 + l];
        float2 w5  = wap[ 5*64 + l];
        float2 w6  = wap[ 6*64 + l];
        float2 w7  = wap[ 7*64 + l];
        float2 w8  = wap[ 8*64 + l];
        float2 w9  = wap[ 9*64 + l];
        float2 w10 = wap[10*64 + l];
        float2 w11 = wap[11*64 + l];
        float2 w12 = wap[12*64 + l];
        u32* dst = &sWA[path][0];
        dst[ 0*64 + l] = bfbits(w0.x)       | (bfbits(w0.y)       << 16);
        dst[ 1*64 + l] = bfbits(w1.x+w4.x)  | (bfbits(w1.y+w4.y)  << 16);
        dst[ 2*64 + l] = bfbits(w2.x)       | (bfbits(w2.y)       << 16);
        dst[ 3*64 + l] = bfbits(w3.x)       | (bfbits(w3.y)       << 16);
        dst[ 4*64 + l] = bfbits(w5.x)       | (bfbits(w5.y)       << 16);
        dst[ 5*64 + l] = bfbits(w6.x)       | (bfbits(w6.y)       << 16);
        dst[ 6*64 + l] = bfbits(w7.x+w10.x) | (bfbits(w7.y+w10.y) << 16);
        dst[ 7*64 + l] = bfbits(w8.x)       | (bfbits(w8.y)       << 16);
        dst[ 8*64 + l] = bfbits(w9.x)       | (bfbits(w9.y)       << 16);
        dst[ 9*64 + l] = bfbits(w11.x)      | (bfbits(w11.y)      << 16);
        dst[10*64 + l] = bfbits(w12.x)      | (bfbits(w12.y)      << 16);
    }
    __syncthreads();                 // ONLY barrier; before any divergent return

    int e = __builtin_amdgcn_readfirstlane(blockIdx.x*4 + wv);
    if (e >= E) return;
    int s0 = __builtin_amdgcn_readfirstlane(seg[e]);
    int s1 = __builtin_amdgcn_readfirstlane(seg[e+1]);
    if (s1 <= s0) { out[(size_t)e*128 + lane] = 0.f; out[(size_t)e*128 + 64 + lane] = 0.f; return; }

    float2 b1k = ((const float2*)Bk1)[lane];
    float2 gk  = ((const float2*)Gkg)[lane];
    float2 bk  = ((const float2*)Bkln)[lane];
    float2 b1v = ((const float2*)Bv1)[lane];
    float2 gv  = ((const float2*)Gvg)[lane];
    float2 bv  = ((const float2*)Bvln)[lane];

    int i0 = __builtin_amdgcn_readfirstlane(col[e]);
    int j0 = __builtin_amdgcn_readfirstlane(row[e]);
    float pix = pos[(size_t)i0*3+0], piy = pos[(size_t)i0*3+1], piz = pos[(size_t)i0*3+2];
    float pjx = pos[(size_t)j0*3+0], pjy = pos[(size_t)j0*3+1], pjz = pos[(size_t)j0*3+2];
    float dxx = pix-pjx, dyy = piy-pjy, dzz = piz-pjz;
    float dist = sqrtf(dxx*dxx + dyy*dyy + dzz*dzz);

    // P2 pre-act for BOTH paths with shared rf (one expf per gaussian)
    float P2ak = b1k.x, P2bk = b1k.y, P2av = b1v.x, P2bv = b1v.y;
    {
        const float2* wbk = (const float2*)(Wk1 + (size_t)148*128);
        const float2* wbv = (const float2*)(Wv1 + (size_t)148*128);
        for (int g2 = 0; g2 < 20; ++g2) {
            float tg = dist - (float)g2 * G_STEP;
            float rf = __expf(G_COEF * tg * tg);
            float2 wk = wbk[g2*64 + lane];
            float2 wu = wbv[g2*64 + lane];
            P2ak += rf * wk.x; P2bk += rf * wk.y;
            P2av += rf * wu.x; P2bv += rf * wu.y;
        }
    }

    // Gk[h] packed bf16 pair -> per-wave LDS (overlay on sS; loop-only lifetime)
    u32* sGkw = &sS[wv][0];          // needs 16*64 u32 <= 16*66 available
    {
        const u32* qrow = (const u32*)(qf + (size_t)e*128);
        #pragma unroll
        for (int h = 0; h < 16; ++h) {
            float g0 = 0.f, g1 = 0.f;
            #pragma unroll
            for (int j = 0; j < 4; ++j) {
                u32 qp = qrow[h*4 + j];
                float ql = lo16(qp), qh = hi16(qp);
                u32 w0 = kw2t[(h*8 + 2*j)*64 + lane];
                u32 w1 = kw2t[(h*8 + 2*j + 1)*64 + lane];
                g0 += ql*lo16(w0) + qh*lo16(w1);
                g1 += ql*hi16(w0) + qh*hi16(w1);
            }
            sGkw[h*64 + lane] = bfbits(g0) | (bfbits(g1) << 16);
        }
    }

    float S0[16], S1[16];
    #pragma unroll
    for (int h = 0; h < 16; ++h) { S0[h] = 0.f; S1[h] = 0.f; }
    float m = -1e30f, sden = 0.f;

    const u32* p1ku = (const u32*)P1k;
    const u32* p1vu = (const u32*)P1v;
    float ax = pjx-pix, ay = pjy-piy, az = pjz-piz;
    int perm = ((lane&1)<<3) | ((lane&2)<<1) | ((lane&4)>>1) | ((lane&8)>>3);

    // 2-ahead prefetch state for triplet pair (X, Y)
    int tB0 = (s0+1 < s1) ? s0+1 : s0;
    int kjX = __builtin_amdgcn_readfirstlane(idx_kj[s0]);
    int knX = __builtin_amdgcn_readfirstlane(idx_k[s0]);
    int kjY = __builtin_amdgcn_readfirstlane(idx_kj[tB0]);
    int knY = __builtin_amdgcn_readfirstlane(idx_k[tB0]);
    u32 fppkX = p1ku[(size_t)kjX*64 + lane], fppvX = p1vu[(size_t)kjX*64 + lane];
    u32 fppkY = p1ku[(size_t)kjY*64 + lane], fppvY = p1vu[(size_t)kjY*64 + lane];
    float fpkxX = pos[(size_t)knX*3+0], fpkyX = pos[(size_t)knX*3+1], fpkzX = pos[(size_t)knX*3+2];
    float fpkxY = pos[(size_t)knY*3+0], fpkyY = pos[(size_t)knY*3+1], fpkzY = pos[(size_t)knY*3+2];

    for (int t = s0; t < s1; t += 2) {
        const bool twoY = (t+1 < s1);
        // consume prefetched
        u32 ppkX = fppkX, ppvX = fppvX, ppkY = fppkY, ppvY = fppvY;
        float bxX = fpkxX-pix, byX = fpkyX-piy, bzX = fpkzX-piz;
        float bxY = fpkxY-pix, byY = fpkyY-piy, bzY = fpkzY-piz;
        // issue next-pair prefetch (clamped; duplicates harmless)
        int tn0 = (t+2 < s1) ? t+2 : s1-1;
        int tn1 = (t+3 < s1) ? t+3 : s1-1;
        kjX = __builtin_amdgcn_readfirstlane(idx_kj[tn0]);
        knX = __builtin_amdgcn_readfirstlane(idx_k[tn0]);
        kjY = __builtin_amdgcn_readfirstlane(idx_kj[tn1]);
        knY = __builtin_amdgcn_readfirstlane(idx_k[tn1]);
        fppkX = p1ku[(size_t)kjX*64 + lane]; fppvX = p1vu[(size_t)kjX*64 + lane];
        fppkY = p1ku[(size_t)kjY*64 + lane]; fppvY = p1vu[(size_t)kjY*64 + lane];
        fpkxX = pos[(size_t)knX*3+0]; fpkyX = pos[(size_t)knX*3+1]; fpkzX = pos[(size_t)knX*3+2];
        fpkxY = pos[(size_t)knY*3+0]; fpkyY = pos[(size_t)knY*3+1]; fpkzY = pos[(size_t)knY*3+2];

        GEOM(X);
        GEOM(Y);

        // pre-activations: k/v paths x triplets X/Y
        float v0kX = P2ak + lo16(ppkX), v1kX = P2bk + hi16(ppkX);
        float v0vX = P2av + lo16(ppvX), v1vX = P2bv + hi16(ppvX);
        float v0kY = P2ak + lo16(ppkY), v1kY = P2bk + hi16(ppkY);
        float v0vY = P2av + lo16(ppvY), v1vY = P2bv + hi16(ppvY);

        FEAT(0,  angX, angY);
        FEAT(1,  s1X,  s1Y);
        FEAT(2,  2.f*s1X*c1X, 2.f*s1Y*c1Y);
        FEAT(3,  s1X*(3.f - 4.f*s1X*s1X), s1Y*(3.f - 4.f*s1Y*s1Y));
        FEAT(4,  shX,  shY);
        FEAT(5,  st3X, st3Y);
        FEAT(6,  c1X,  c1Y);
        FEAT(7,  1.f - 2.f*s1X*s1X, 1.f - 2.f*s1Y*s1Y);
        FEAT(8,  c1X*(4.f*c1X*c1X - 3.f), c1Y*(4.f*c1Y*c1Y - 3.f));
        FEAT(9,  chX,  chY);
        FEAT(10, ct3X, ct3Y);

        // 4 independent LN chains (compiler interleaves)
        float totKX, tot2KX, totVX, tot2VX, totKY, tot2KY, totVY, tot2VY;
        LNSTATS(v0kX, v1kX, totKX, tot2KX);
        LNSTATS(v0vX, v1vX, totVX, tot2VX);
        LNSTATS(v0kY, v1kY, totKY, tot2KY);
        LNSTATS(v0vY, v1vY, totVY, tot2VY);
        float h0kX, h1kX, h0vX, h1vX, h0kY, h1kY, h0vY, h1vY;
        LNAPPLY(totKX, tot2KX, v0kX, v1kX, gk, bk, h0kX, h1kX);
        LNAPPLY(totVX, tot2VX, v0vX, v1vX, gv, bv, h0vX, h1vX);
        LNAPPLY(totKY, tot2KY, v0kY, v1kY, gk, bk, h0kY, h1kY);
        LNAPPLY(totVY, tot2VY, v0vY, v1vY, gv, bv, h0vY, h1vY);

        // per-head logit partials (Gk from per-wave LDS, read once for X and Y)
        float pX[16], pY[16];
        #pragma unroll
        for (int h = 0; h < 16; ++h) {
            u32 g = sGkw[h*64 + lane];
            float gl = lo16(g), gh = hi16(g);
            pX[h] = h0kX*gl + h1kX*gh;
            pY[h] = h0kY*gl + h1kY*gh;
        }
        float lgX, lgY;
        BFLY(pX, lgX);
        BFLY(pY, lgY);

        // online softmax (pair): one deferred-max check covers both logits
        float mx = fmaxf(lgX, lgY);
        if (__any(mx > m + 8.f)) {
            float nm = fmaxf(m, mx);
            float fac = __expf(m - nm);
            sden *= fac; m = nm;
            #pragma unroll
            for (int h = 0; h < 16; ++h) {
                float fh = __shfl(fac, PERM4(h), 64);
                S0[h] *= fh; S1[h] *= fh;
            }
        }
        float exX = __expf(lgX - m);
        float exY = twoY ? __expf(lgY - m) : 0.f;   // masked tail: no double count
        sden += exX + exY;
        // broadcast via per-wave LDS (replaces 16 ds_bpermute)
        if (lane < 16) sEx[wv][perm] = make_float2(exX, exY);
        #pragma unroll
        for (int h = 0; h < 16; ++h) {
            float2 eh = sEx[wv][h];
            S0[h] += eh.x*h0vX + eh.y*h0vY;
            S1[h] += eh.x*h1vX + eh.y*h1vY;
        }
    }

    // normalize by softmax denominator while staging S as bf16 pairs
    float inv = 1.f / sden;
    #pragma unroll
    for (int h = 0; h < 16; ++h) {
        float sc = __shfl(inv, PERM4(h), 64);
        sS[wv][h*66 + lane] = bfbits(S0[h]*sc) | (bfbits(S1[h]*sc) << 16);
    }
    __threadfence_block();
    // projection: out[o] = sum_d S[o>>3][d]*Wv2[d][o] + b2[o]
    int h0i = lane >> 3, h1i = 8 + (lane >> 3);
    float acc0 = B2v[lane], acc1 = B2v[lane + 64];
    const u32* sr0 = &sS[wv][h0i*66];
    const u32* sr1 = &sS[wv][h1i*66];
    #pragma unroll 8
    for (int j = 0; j < 64; ++j) {
        u32 us0 = sr0[j], uw0 = vw2t[j*128 + lane];
        u32 us1 = sr1[j], uw1 = vw2t[j*128 + 64 + lane];
        acc0 += lo16(us0)*lo16(uw0) + hi16(us0)*hi16(uw0);
        acc1 += lo16(us1)*lo16(uw1) + hi16(us1)*hi16(uw1);
    }
    out[(size_t)e*128 + lane] = acc0;
    out[(size_t)e*128 + 64 + lane] = acc1;
}

extern "C" void kernel_launch(void* const* d_in, const int* in_sizes, int n_in,
                              void* d_out, int out_size, void* d_ws, size_t ws_size,
                              hipStream_t stream)
{
    const float* h_bond = (const float*)d_in[1];
    const float* pos    = (const float*)d_in[2];
    const float* hkW1 = (const float*)d_in[3];
    const float* hkb1 = (const float*)d_in[4];
    const float* hkg  = (const float*)d_in[5];
    const float* hkb  = (const float*)d_in[6];
    const float* hkW2 = (const float*)d_in[7];
    const float* hvW1 = (const float*)d_in[9];
    const float* hvb1 = (const float*)d_in[10];
    const float* hvg  = (const float*)d_in[11];
    const float* hvb  = (const float*)d_in[12];
    const float* hvW2 = (const float*)d_in[13];
    const float* hvb2 = (const float*)d_in[14];
    const float* hqW1 = (const float*)d_in[15];
    const float* hqb1 = (const float*)d_in[16];
    const float* hqg  = (const float*)d_in[17];
    const float* hqb  = (const float*)d_in[18];
    const float* hqW2 = (const float*)d_in[19];
    const float* hqb2 = (const float*)d_in[20];
    const int* row    = (const int*)d_in[21];
    const int* col    = (const int*)d_in[22];
    const int* idx_k  = (const int*)d_in[25];
    const int* idx_kj = (const int*)d_in[26];
    const int* idx_ji = (const int*)d_in[27];

    int E = in_sizes[21];
    int T = in_sizes[27];

    char* w = (char*)d_ws;
    size_t off = 0;
    auto carve = [&](size_t bytes) -> void* {
        void* p = w + off;
        off = (off + bytes + 255) & ~(size_t)255;
        return p;
    };
    int*  seg   = (int*) carve(((size_t)E + 1) * sizeof(int));
    bf16* qf    = (bf16*)carve((size_t)E * 128 * sizeof(bf16));
    bf16* P1k   = (bf16*)carve((size_t)E * 128 * sizeof(bf16));
    bf16* P1v   = (bf16*)carve((size_t)E * 128 * sizeof(bf16));
    u32*  kw2t  = (u32*) carve(8192 * sizeof(u32));
    u32*  vw2t  = (u32*) carve(8192 * sizeof(u32));

    if (off > ws_size) {
        marker_kernel<<<(out_size + 255)/256, 256, 0, stream>>>((float*)d_out, out_size);
        return;
    }

    int gq = (E + 15)/16;
    int gw = (E + 3)/4;
    seg_start_kernel<<<(E + 1 + 255)/256, 256, 0, stream>>>(idx_ji, T, seg, E);
    pack_w2<<<32, 256, 0, stream>>>(hkW2, hvW2, kw2t, vw2t);
    q_kernel<<<gq, 128, 0, stream>>>(hqW1, hqb1, hqg, hqb, hqW2, hqb2, h_bond, qf, E);
    p_prep2<<<gq, 128, 0, stream>>>(hkW1, hvW1, h_bond, pos, row, col, P1k, P1v, E);
    fused_kernel<<<gw, 256, 0, stream>>>(kw2t, vw2t,
        hkW1, hkb1, hkg, hkb,
        hvW1, hvb1, hvg, hvb,
        hvb2, qf, P1k, P1v, pos, seg, idx_kj, idx_k, row, col, (float*)d_out, E);
}

// Round 11
// 1661.534 us; speedup vs baseline: 2.4090x; 1.0147x over previous
//
#include <hip/hip_runtime.h>
#include <hip/hip_bf16.h>
#include <math.h>

typedef __hip_bfloat16 bf16;
typedef unsigned int u32;

__device__ __forceinline__ float b2f(bf16 x){ return __bfloat162float(x); }
__device__ __forceinline__ bf16  f2b(float x){ return __float2bfloat16(x); }
__device__ __forceinline__ float lo16(u32 u){ return __uint_as_float(u << 16); }
__device__ __forceinline__ float hi16(u32 u){ return __uint_as_float(u & 0xFFFF0000u); }
// float -> bf16 bits with round-to-nearest-even
__device__ __forceinline__ u32 bfbits(float x){
    u32 u = __float_as_uint(x);
    return (u + 0x7FFFu + ((u >> 16) & 1u)) >> 16;
}

#define RSQRT8 0.35355339059327373f
#define G_STEP (10.0f/19.0f)
#define G_COEF (-0.5f/(G_STEP*G_STEP))

// butterfly layout involution: lane l holds head PERM4(l&15); PERM4 is self-inverse
__device__ __forceinline__ constexpr int PERM4(int h){
    return ((h&1)<<3) | ((h&2)<<1) | ((h&4)>>1) | ((h&8)>>3);
}

// fast atan2 for y >= 0 (result in [0, pi]); poly max err ~1.6e-6 rad
__device__ __forceinline__ float fast_atan2(float y, float x){
    float ax = fabsf(x);
    float mn = fminf(y, ax), mx = fmaxf(y, ax);
    float t = mn / fmaxf(mx, 1e-30f);
    float s = t*t;
    float p = t * (0.99997726f + s*(-0.33262347f + s*(0.19354346f +
              s*(-0.11643287f + s*(0.05265332f + s*(-0.01172120f))))));
    float r = (y > ax) ? (1.5707963267948966f - p) : p;
    r = (x < 0.f) ? (3.14159265358979323f - r) : r;
    return r;
}

// inputs are PROVEN f32

// ---------------- seg starts (idx_ji sorted) ----------------
__global__ void seg_start_kernel(const int* __restrict__ idx_ji, int T,
                                 int* __restrict__ seg, int E)
{
    int e = blockIdx.x * blockDim.x + threadIdx.x;
    if (e > E) return;
    int lo = 0, hi = T;
    while (lo < hi) { int mid = (lo + hi) >> 1; if (idx_ji[mid] < e) lo = mid + 1; else hi = mid; }
    seg[e] = lo;
}

__global__ void marker_kernel(float* out, int n){
    int i = blockIdx.x * blockDim.x + threadIdx.x;
    if (i < n) out[i] = 12345.0f;
}

// ---------------- pack W2 matrices to bf16-pair layouts (L2-resident) --------
__global__ void pack_w2(const float* __restrict__ Wk2, const float* __restrict__ Wv2,
                        u32* __restrict__ kw2t, u32* __restrict__ vw2t)
{
    int idx = blockIdx.x*256 + threadIdx.x;
    if (idx >= 8192) return;
    int c = idx >> 6, p = idx & 63;
    kw2t[idx] = bfbits(Wk2[(size_t)(2*p)*128 + c]) | (bfbits(Wk2[(size_t)(2*p+1)*128 + c]) << 16);
    int j = idx >> 7, o = idx & 127;
    vw2t[idx] = bfbits(Wv2[(size_t)(2*j)*128 + o]) | (bfbits(Wv2[(size_t)(2*j+1)*128 + o]) << 16);
}

// ---------------- q = MLP_hq(h_bond) per edge -> bf16, 4-edge batched --------
__global__ __launch_bounds__(128) void q_kernel(
    const float* __restrict__ W1, const float* __restrict__ B1,
    const float* __restrict__ G,  const float* __restrict__ Bln,
    const float* __restrict__ W2, const float* __restrict__ B2,
    const float* __restrict__ h_bond, bf16* __restrict__ qout, int E)
{
    __shared__ u32 sW[128*65];
    __shared__ float sH[16][130];
    __shared__ float sX[4][130];
    __shared__ float sRed[4][4];
    int tid = threadIdx.x; int wv = tid>>6, lane = tid&63;
    int base = blockIdx.x * 16;

    for (int idx = tid; idx < 128*128; idx += 128) {
        int i = idx >> 7, d = idx & 127;
        ((bf16*)sW)[d*130 + i] = f2b(W1[idx]);
    }
    __syncthreads();
    for (int e4 = 0; e4 < 16; e4 += 4) {
        #pragma unroll
        for (int q = 0; q < 4; ++q) {
            int e = base + e4 + q;
            sX[q][tid] = (e < E) ? h_bond[(size_t)e*128 + tid] : 0.f;
        }
        __syncthreads();
        float b1t = B1[tid];
        float ac[4] = {b1t, b1t, b1t, b1t};
        const u32* wrow = &sW[tid*65];
        #pragma unroll 4
        for (int j = 0; j < 64; ++j) {
            u32 w = wrow[j]; float wl = lo16(w), wh = hi16(w);
            #pragma unroll
            for (int q = 0; q < 4; ++q)
                ac[q] += sX[q][2*j]*wl + sX[q][2*j+1]*wh;
        }
        float s1v[4], s2v[4];
        #pragma unroll
        for (int q = 0; q < 4; ++q) { s1v[q] = ac[q]; s2v[q] = ac[q]*ac[q]; }
        #pragma unroll
        for (int m = 1; m < 64; m <<= 1) {
            #pragma unroll
            for (int q = 0; q < 4; ++q) {
                s1v[q] += __shfl_xor(s1v[q], m, 64);
                s2v[q] += __shfl_xor(s2v[q], m, 64);
            }
        }
        if (lane == 0) {
            #pragma unroll
            for (int q = 0; q < 4; ++q) { sRed[q][wv*2] = s1v[q]; sRed[q][wv*2+1] = s2v[q]; }
        }
        __syncthreads();
        float gt = G[tid], bt = Bln[tid];
        #pragma unroll
        for (int q = 0; q < 4; ++q) {
            float tot = sRed[q][0] + sRed[q][2], tot2 = sRed[q][1] + sRed[q][3];
            float mu = tot * (1.f/128.f);
            float var = fmaxf(tot2 * (1.f/128.f) - mu*mu, 0.f);
            float nv = gt * (ac[q] - mu) * rsqrtf(var + 1e-5f) + bt;
            sH[e4+q][tid] = fmaxf(nv, 0.f);
        }
        __syncthreads();
    }
    for (int idx = tid; idx < 128*128; idx += 128) {
        int i = idx >> 7, d = idx & 127;
        ((bf16*)sW)[d*130 + i] = f2b(W2[idx]);
    }
    __syncthreads();
    for (int e4 = 0; e4 < 16; e4 += 4) {
        float b2t = B2[tid];
        float ac[4] = {b2t, b2t, b2t, b2t};
        const u32* wrow = &sW[tid*65];
        #pragma unroll 4
        for (int j = 0; j < 64; ++j) {
            u32 w = wrow[j]; float wl = lo16(w), wh = hi16(w);
            #pragma unroll
            for (int q = 0; q < 4; ++q)
                ac[q] += sH[e4+q][2*j]*wl + sH[e4+q][2*j+1]*wh;
        }
        #pragma unroll
        for (int q = 0; q < 4; ++q) {
            int e = base + e4 + q;
            if (e < E) qout[(size_t)e*128 + tid] = f2b(ac[q]);
        }
    }
}

// ---------------- P1[e] = h_bond[e]@W1[0:128] + rfeat[e]@W1[128:148] -> bf16 --
// R5/R7-proven: LDS-staged weights, 4-edge batched. (R10's merged p_prep2 with
// both matrices in 76.8KB LDS dropped to 2 blocks/CU and was ~23us slower.)
__global__ __launch_bounds__(128) void p_prep(
    const float* __restrict__ W1, const float* __restrict__ h_bond,
    const float* __restrict__ pos, const int* __restrict__ row,
    const int* __restrict__ col, bf16* __restrict__ P1, int E)
{
    __shared__ u32 sW[128*75];       // [dim][row-pair], 148 rows -> 74 pairs, stride 150 bf16
    __shared__ float sX[4][152];
    int tid = threadIdx.x;
    for (int idx = tid; idx < 148*128; idx += 128) {
        int i = idx >> 7, d = idx & 127;
        ((bf16*)sW)[d*150 + i] = f2b(W1[idx]);
    }
    __syncthreads();
    int base = blockIdx.x * 16;
    for (int e4 = 0; e4 < 16; e4 += 4) {
        #pragma unroll
        for (int q = 0; q < 4; ++q) {
            int e = base + e4 + q;
            sX[q][tid] = (e < E) ? h_bond[(size_t)e*128 + tid] : 0.f;
        }
        if (tid < 80) {
            int q = tid / 20, g = tid % 20;
            int e = base + e4 + q;
            float rf = 0.f;
            if (e < E) {
                int i0 = col[e], j0 = row[e];
                float dx = pos[(size_t)i0*3+0] - pos[(size_t)j0*3+0];
                float dy = pos[(size_t)i0*3+1] - pos[(size_t)j0*3+1];
                float dz = pos[(size_t)i0*3+2] - pos[(size_t)j0*3+2];
                float dist = sqrtf(dx*dx + dy*dy + dz*dz);
                float t = dist - (float)g * G_STEP;
                rf = __expf(G_COEF * t * t);
            }
            sX[q][128 + g] = rf;
        }
        __syncthreads();
        float acc0 = 0.f, acc1 = 0.f, acc2 = 0.f, acc3 = 0.f;
        const u32* wrow = &sW[tid*75];
        #pragma unroll 4
        for (int j = 0; j < 74; ++j) {
            u32 w = wrow[j]; float wl = lo16(w), wh = hi16(w);
            acc0 += sX[0][2*j]*wl + sX[0][2*j+1]*wh;
            acc1 += sX[1][2*j]*wl + sX[1][2*j+1]*wh;
            acc2 += sX[2][2*j]*wl + sX[2][2*j+1]*wh;
            acc3 += sX[3][2*j]*wl + sX[3][2*j+1]*wh;
        }
        int e = base + e4;
        if (e   < E) P1[(size_t)e*128     + tid] = f2b(acc0);
        if (e+1 < E) P1[(size_t)(e+1)*128 + tid] = f2b(acc1);
        if (e+2 < E) P1[(size_t)(e+2)*128 + tid] = f2b(acc2);
        if (e+3 < E) P1[(size_t)(e+3)*128 + tid] = f2b(acc3);
        __syncthreads();
    }
}

// per-edge P2 pre-act (gaussian part + b1) -- R7's per-path loop (the R10
// merged 4-accumulator variant measured ~3.6% slower)
#define EDGE_P2(W1full, b1v_, P2a_, P2b_) \
    float P2a_ = b1v_.x, P2b_ = b1v_.y; \
    { const float2* wbp = (const float2*)((W1full) + (size_t)148*128); \
      for (int g2 = 0; g2 < 20; ++g2) { \
        float tg = dist - (float)g2 * G_STEP; \
        float rf = __expf(G_COEF * tg * tg); \
        float2 wb = wbp[g2*64 + lane]; \
        P2a_ += rf * wb.x; \
        P2b_ += rf * wb.y; \
      } }

// geometry + trig identities for one triplet (suffix S)
#define GEOM(S) \
    float dt##S = ax*bx##S + ay*by##S + az*bz##S; \
    float cxx##S = ay*bz##S - az*by##S, cyy##S = az*bx##S - ax*bz##S, czz##S = ax*by##S - ay*bx##S; \
    float bb##S = cxx##S*cxx##S + cyy##S*cyy##S + czz##S*czz##S; \
    float bc##S = sqrtf(bb##S); \
    float ih##S = rsqrtf(fmaxf(dt##S*dt##S + bb##S, 1e-30f)); \
    float c1##S = dt##S * ih##S, s1##S = bc##S * ih##S; \
    float ang##S = fast_atan2(bc##S, dt##S); \
    float sh##S = sqrtf(fmaxf(0.5f*(1.f - c1##S), 0.f)); \
    float ch##S = sqrtf(fmaxf(0.5f*(1.f + c1##S), 0.f)); \
    float st3##S, ct3##S; __sincosf((1.f/3.f)*ang##S, &st3##S, &ct3##S);

// one feature: ONE ds_read_b64 gives both paths' weight pair (R11: was 2x b32)
#define FEAT(fidx, valX, valY) { \
    uint2 wp_ = sWAp[(fidx)*64 + lane]; \
    float wkl_ = lo16(wp_.x), wkh_ = hi16(wp_.x), wvl_ = lo16(wp_.y), wvh_ = hi16(wp_.y); \
    float fx_ = (valX), fy_ = (valY); \
    v0kX += fx_*wkl_; v1kX += fx_*wkh_; v0vX += fx_*wvl_; v1vX += fx_*wvh_; \
    v0kY += fy_*wkl_; v1kY += fy_*wkh_; v0vY += fy_*wvl_; v1vY += fy_*wvh_; }

// 7-shfl split reduction: (sum, sumsq) over 128 dims
#define LNSTATS(v0_, v1_, TOT, TOT2) { \
    float sum_ = (v0_) + (v1_), ssq_ = (v0_)*(v0_) + (v1_)*(v1_); \
    float r_ = ((lane&1) ? ssq_ : sum_) + __shfl_xor((lane&1) ? sum_ : ssq_, 1, 64); \
    r_ += __shfl_xor(r_, 2, 64);  r_ += __shfl_xor(r_, 4, 64); \
    r_ += __shfl_xor(r_, 8, 64);  r_ += __shfl_xor(r_, 16, 64); \
    r_ += __shfl_xor(r_, 32, 64); \
    float o_ = __shfl_xor(r_, 1, 64); \
    TOT = (lane&1) ? o_ : r_;  TOT2 = (lane&1) ? r_ : o_; }

#define LNAPPLY(TOT, TOT2, v0_, v1_, g_, b_, H0, H1) { \
    float mu_ = (TOT) * (1.f/128.f); \
    float var_ = fmaxf((TOT2) * (1.f/128.f) - mu_*mu_, 0.f); \
    float rs_ = rsqrtf(var_ + 1e-5f); \
    H0 = fmaxf(g_.x*((v0_)-mu_)*rs_ + b_.x, 0.f); \
    H1 = fmaxf(g_.y*((v1_)-mu_)*rs_ + b_.y, 0.f); }

// 17-shfl split-exchange butterfly: 16 reductions -> LG (head PERM4(lane&15))
#define BFLY(P, LG) { \
    float a8_[8]; \
    { int up_ = lane & 1; \
      _Pragma("unroll") \
      for (int i_ = 0; i_ < 8; ++i_) { \
        float kp_ = up_ ? P[i_+8] : P[i_]; \
        float sd_ = up_ ? P[i_]   : P[i_+8]; \
        a8_[i_] = kp_ + __shfl_xor(sd_, 1, 64); } } \
    float a4_[4]; \
    { int up_ = lane & 2; \
      _Pragma("unroll") \
      for (int i_ = 0; i_ < 4; ++i_) { \
        float kp_ = up_ ? a8_[i_+4] : a8_[i_]; \
        float sd_ = up_ ? a8_[i_]   : a8_[i_+4]; \
        a4_[i_] = kp_ + __shfl_xor(sd_, 2, 64); } } \
    float a2_[2]; \
    { int up_ = lane & 4; \
      _Pragma("unroll") \
      for (int i_ = 0; i_ < 2; ++i_) { \
        float kp_ = up_ ? a4_[i_+2] : a4_[i_]; \
        float sd_ = up_ ? a4_[i_]   : a4_[i_+2]; \
        a2_[i_] = kp_ + __shfl_xor(sd_, 4, 64); } } \
    float a1_; \
    { int up_ = lane & 8; \
      float kp_ = up_ ? a2_[1] : a2_[0]; \
      float sd_ = up_ ? a2_[0] : a2_[1]; \
      a1_ = kp_ + __shfl_xor(sd_, 8, 64); } \
    a1_ += __shfl_xor(a1_, 16, 64); \
    a1_ += __shfl_xor(a1_, 32, 64); \
    LG = a1_ * RSQRT8; }

// ---------------- fused: logits + online softmax + v-path + projection -------
// R11: R7's proven 4-wave structure (953us, VALUBusy 79%, zero spill) with one
// contained change: DS-issue-slot reduction. Angular weights for BOTH paths
// packed in one uint2 (FEAT: 22 -> 11 ds_read_b64 per pair) and Gk head-pairs
// packed (16 -> 8 ds_read_b64 per pair): ~19 fewer DS issue slots per pair,
// ~35% of DS instructions, no live-set change.
__global__ __launch_bounds__(256, 2)
void fused_kernel(
    const u32* __restrict__ kw2t, const u32* __restrict__ vw2t,
    const float* __restrict__ Wk1, const float* __restrict__ Bk1,
    const float* __restrict__ Gkg, const float* __restrict__ Bkln,
    const float* __restrict__ Wv1, const float* __restrict__ Bv1,
    const float* __restrict__ Gvg, const float* __restrict__ Bvln,
    const float* __restrict__ B2v,
    const bf16* __restrict__ qf, const bf16* __restrict__ P1k, const bf16* __restrict__ P1v,
    const float* __restrict__ pos, const int* __restrict__ seg,
    const int* __restrict__ idx_kj, const int* __restrict__ idx_k,
    const int* __restrict__ row, const int* __restrict__ col,
    float* __restrict__ out, int E)
{
    __shared__ u32 sS[4][16*66];     // epilogue staging; loop-time overlay holds Gk pairs
    __shared__ uint2 sWAp[11*64];    // angular weight pairs: .x = k-path, .y = v-path
    __shared__ float2 sEx[4][16];    // per-wave (exX, exY) per head
    int tid = threadIdx.x, lane = tid & 63, wv = tid >> 6;

    // block-cooperative populate of sWAp. Feature order:
    // {ang, s1, s2, s3, sh, st3, c1, c2, c3, ch, ct3}; s1 at {1,4}, c1 at {7,10} folded.
    // path p writes word p of each uint2 (once per block; stride-2 writes are fine).
    if (tid < 128) {
        int path = tid >> 6, l = tid & 63;
        const float* W1full = path ? Wv1 : Wk1;
        const float2* wap = (const float2*)(W1full + (size_t)168*128);
        float2 w0  = wap[ 0*64 + l];
        float2 w1  = wap[ 1*64 + l];
        float2 w2  = wap[ 2*64 + l];
        float2 w3  = wap[ 3*64 + l];
        float2 w4  = wap[ 4*64 + l];
        float2 w5  = wap[ 5*64 + l];
        float2 w6  = wap[ 6*64 + l];
        float2 w7  = wap[ 7*64 + l];
        float2 w8  = wap[ 8*64 + l];
        float2 w9  = wap[ 9*64 + l];
        float2 w10 = wap[10*64 + l];
        float2 w11 = wap[11*64 + l];
        float2 w12 = wap[12*64 + l];
        u32* dst = ((u32*)sWAp) + path;   // interleaved: [f*64+l].x / .y
        dst[( 0*64 + l)*2] = bfbits(w0.x)       | (bfbits(w0.y)       << 16);
        dst[( 1*64 + l)*2] = bfbits(w1.x+w4.x)  | (bfbits(w1.y+w4.y)  << 16);
        dst[( 2*64 + l)*2] = bfbits(w2.x)       | (bfbits(w2.y)       << 16);
        dst[( 3*64 + l)*2] = bfbits(w3.x)       | (bfbits(w3.y)       << 16);
        dst[( 4*64 + l)*2] = bfbits(w5.x)       | (bfbits(w5.y)       << 16);
        dst[( 5*64 + l)*2] = bfbits(w6.x)       | (bfbits(w6.y)       << 16);
        dst[( 6*64 + l)*2] = bfbits(w7.x+w10.x) | (bfbits(w7.y+w10.y) << 16);
        dst[( 7*64 + l)*2] = bfbits(w8.x)       | (bfbits(w8.y)       << 16);
        dst[( 8*64 + l)*2] = bfbits(w9.x)       | (bfbits(w9.y)       << 16);
        dst[( 9*64 + l)*2] = bfbits(w11.x)      | (bfbits(w11.y)      << 16);
        dst[(10*64 + l)*2] = bfbits(w12.x)      | (bfbits(w12.y)      << 16);
    }
    __syncthreads();                 // ONLY barrier; before any divergent return

    int e = __builtin_amdgcn_readfirstlane(blockIdx.x*4 + wv);
    if (e >= E) return;
    int s0 = __builtin_amdgcn_readfirstlane(seg[e]);
    int s1 = __builtin_amdgcn_readfirstlane(seg[e+1]);
    if (s1 <= s0) { out[(size_t)e*128 + lane] = 0.f; out[(size_t)e*128 + 64 + lane] = 0.f; return; }

    float2 b1k = ((const float2*)Bk1)[lane];
    float2 gk  = ((const float2*)Gkg)[lane];
    float2 bk  = ((const float2*)Bkln)[lane];
    float2 b1v = ((const float2*)Bv1)[lane];
    float2 gv  = ((const float2*)Gvg)[lane];
    float2 bv  = ((const float2*)Bvln)[lane];

    int i0 = __builtin_amdgcn_readfirstlane(col[e]);
    int j0 = __builtin_amdgcn_readfirstlane(row[e]);
    float pix = pos[(size_t)i0*3+0], piy = pos[(size_t)i0*3+1], piz = pos[(size_t)i0*3+2];
    float pjx = pos[(size_t)j0*3+0], pjy = pos[(size_t)j0*3+1], pjz = pos[(size_t)j0*3+2];
    float dxx = pix-pjx, dyy = piy-pjy, dzz = piz-pjz;
    float dist = sqrtf(dxx*dxx + dyy*dyy + dzz*dzz);

    EDGE_P2(Wk1, b1k, P2ak, P2bk);
    EDGE_P2(Wv1, b1v, P2av, P2bv);

    // Gk head-pairs packed as uint2 -> per-wave LDS (overlay on sS).
    // sS[wv] base is 4224-byte aligned; 8*64 uint2 = 4096 B fits in 16*66 u32.
    uint2* sGk2 = (uint2*)&sS[wv][0];
    {
        const u32* qrow = (const u32*)(qf + (size_t)e*128);
        #pragma unroll
        for (int hp = 0; hp < 8; ++hp) {
            u32 pk[2];
            #pragma unroll
            for (int s = 0; s < 2; ++s) {
                int h = 2*hp + s;
                float g0 = 0.f, g1 = 0.f;
                #pragma unroll
                for (int j = 0; j < 4; ++j) {
                    u32 qp = qrow[h*4 + j];
                    float ql = lo16(qp), qh = hi16(qp);
                    u32 w0 = kw2t[(h*8 + 2*j)*64 + lane];
                    u32 w1 = kw2t[(h*8 + 2*j + 1)*64 + lane];
                    g0 += ql*lo16(w0) + qh*lo16(w1);
                    g1 += ql*hi16(w0) + qh*hi16(w1);
                }
                pk[s] = bfbits(g0) | (bfbits(g1) << 16);
            }
            sGk2[hp*64 + lane] = make_uint2(pk[0], pk[1]);
        }
    }

    float S0[16], S1[16];
    #pragma unroll
    for (int h = 0; h < 16; ++h) { S0[h] = 0.f; S1[h] = 0.f; }
    float m = -1e30f, sden = 0.f;

    const u32* p1ku = (const u32*)P1k;
    const u32* p1vu = (const u32*)P1v;
    float ax = pjx-pix, ay = pjy-piy, az = pjz-piz;
    int perm = ((lane&1)<<3) | ((lane&2)<<1) | ((lane&4)>>1) | ((lane&8)>>3);

    // 2-ahead prefetch state for triplet pair (X, Y)
    int tB0 = (s0+1 < s1) ? s0+1 : s0;
    int kjX = __builtin_amdgcn_readfirstlane(idx_kj[s0]);
    int knX = __builtin_amdgcn_readfirstlane(idx_k[s0]);
    int kjY = __builtin_amdgcn_readfirstlane(idx_kj[tB0]);
    int knY = __builtin_amdgcn_readfirstlane(idx_k[tB0]);
    u32 fppkX = p1ku[(size_t)kjX*64 + lane], fppvX = p1vu[(size_t)kjX*64 + lane];
    u32 fppkY = p1ku[(size_t)kjY*64 + lane], fppvY = p1vu[(size_t)kjY*64 + lane];
    float fpkxX = pos[(size_t)knX*3+0], fpkyX = pos[(size_t)knX*3+1], fpkzX = pos[(size_t)knX*3+2];
    float fpkxY = pos[(size_t)knY*3+0], fpkyY = pos[(size_t)knY*3+1], fpkzY = pos[(size_t)knY*3+2];

    for (int t = s0; t < s1; t += 2) {
        const bool twoY = (t+1 < s1);
        // consume prefetched
        u32 ppkX = fppkX, ppvX = fppvX, ppkY = fppkY, ppvY = fppvY;
        float bxX = fpkxX-pix, byX = fpkyX-piy, bzX = fpkzX-piz;
        float bxY = fpkxY-pix, byY = fpkyY-piy, bzY = fpkzY-piz;
        // issue next-pair prefetch (clamped; duplicates harmless)
        int tn0 = (t+2 < s1) ? t+2 : s1-1;
        int tn1 = (t+3 < s1) ? t+3 : s1-1;
        kjX = __builtin_amdgcn_readfirstlane(idx_kj[tn0]);
        knX = __builtin_amdgcn_readfirstlane(idx_k[tn0]);
        kjY = __builtin_amdgcn_readfirstlane(idx_kj[tn1]);
        knY = __builtin_amdgcn_readfirstlane(idx_k[tn1]);
        fppkX = p1ku[(size_t)kjX*64 + lane]; fppvX = p1vu[(size_t)kjX*64 + lane];
        fppkY = p1ku[(size_t)kjY*64 + lane]; fppvY = p1vu[(size_t)kjY*64 + lane];
        fpkxX = pos[(size_t)knX*3+0]; fpkyX = pos[(size_t)knX*3+1]; fpkzX = pos[(size_t)knX*3+2];
        fpkxY = pos[(size_t)knY*3+0]; fpkyY = pos[(size_t)knY*3+1]; fpkzY = pos[(size_t)knY*3+2];

        GEOM(X);
        GEOM(Y);

        // pre-activations: k/v paths x triplets X/Y
        float v0kX = P2ak + lo16(ppkX), v1kX = P2bk + hi16(ppkX);
        float v0vX = P2av + lo16(ppvX), v1vX = P2bv + hi16(ppvX);
        float v0kY = P2ak + lo16(ppkY), v1kY = P2bk + hi16(ppkY);
        float v0vY = P2av + lo16(ppvY), v1vY = P2bv + hi16(ppvY);

        FEAT(0,  angX, angY);
        FEAT(1,  s1X,  s1Y);
        FEAT(2,  2.f*s1X*c1X, 2.f*s1Y*c1Y);
        FEAT(3,  s1X*(3.f - 4.f*s1X*s1X), s1Y*(3.f - 4.f*s1Y*s1Y));
        FEAT(4,  shX,  shY);
        FEAT(5,  st3X, st3Y);
        FEAT(6,  c1X,  c1Y);
        FEAT(7,  1.f - 2.f*s1X*s1X, 1.f - 2.f*s1Y*s1Y);
        FEAT(8,  c1X*(4.f*c1X*c1X - 3.f), c1Y*(4.f*c1Y*c1Y - 3.f));
        FEAT(9,  chX,  chY);
        FEAT(10, ct3X, ct3Y);

        // 4 independent LN chains (compiler interleaves)
        float totKX, tot2KX, totVX, tot2VX, totKY, tot2KY, totVY, tot2VY;
        LNSTATS(v0kX, v1kX, totKX, tot2KX);
        LNSTATS(v0vX, v1vX, totVX, tot2VX);
        LNSTATS(v0kY, v1kY, totKY, tot2KY);
        LNSTATS(v0vY, v1vY, totVY, tot2VY);
        float h0kX, h1kX, h0vX, h1vX, h0kY, h1kY, h0vY, h1vY;
        LNAPPLY(totKX, tot2KX, v0kX, v1kX, gk, bk, h0kX, h1kX);
        LNAPPLY(totVX, tot2VX, v0vX, v1vX, gv, bv, h0vX, h1vX);
        LNAPPLY(totKY, tot2KY, v0kY, v1kY, gk, bk, h0kY, h1kY);
        LNAPPLY(totVY, tot2VY, v0vY, v1vY, gv, bv, h0vY, h1vY);

        // per-head logit partials (Gk head-pairs from LDS: 8 ds_read_b64)
        float pX[16], pY[16];
        #pragma unroll
        for (int hp = 0; hp < 8; ++hp) {
            uint2 gg = sGk2[hp*64 + lane];
            float gl0 = lo16(gg.x), gh0 = hi16(gg.x);
            float gl1 = lo16(gg.y), gh1 = hi16(gg.y);
            pX[2*hp]   = h0kX*gl0 + h1kX*gh0;
            pX[2*hp+1] = h0kX*gl1 + h1kX*gh1;
            pY[2*hp]   = h0kY*gl0 + h1kY*gh0;
            pY[2*hp+1] = h0kY*gl1 + h1kY*gh1;
        }
        float lgX, lgY;
        BFLY(pX, lgX);
        BFLY(pY, lgY);

        // online softmax (pair): one deferred-max check covers both logits
        float mx = fmaxf(lgX, lgY);
        if (__any(mx > m + 8.f)) {
            float nm = fmaxf(m, mx);
            float fac = __expf(m - nm);
            sden *= fac; m = nm;
            #pragma unroll
            for (int h = 0; h < 16; ++h) {
                float fh = __shfl(fac, PERM4(h), 64);
                S0[h] *= fh; S1[h] *= fh;
            }
        }
        float exX = __expf(lgX - m);
        float exY = twoY ? __expf(lgY - m) : 0.f;   // masked tail: no double count
        sden += exX + exY;
        // broadcast via per-wave LDS (replaces 16 ds_bpermute)
        if (lane < 16) sEx[wv][perm] = make_float2(exX, exY);
        #pragma unroll
        for (int h = 0; h < 16; ++h) {
            float2 eh = sEx[wv][h];
            S0[h] += eh.x*h0vX + eh.y*h0vY;
            S1[h] += eh.x*h1vX + eh.y*h1vY;
        }
    }

    // normalize by softmax denominator while staging S as bf16 pairs
    float inv = 1.f / sden;
    #pragma unroll
    for (int h = 0; h < 16; ++h) {
        float sc = __shfl(inv, PERM4(h), 64);
        sS[wv][h*66 + lane] = bfbits(S0[h]*sc) | (bfbits(S1[h]*sc) << 16);
    }
    __threadfence_block();
    // projection: out[o] = sum_d S[o>>3][d]*Wv2[d][o] + b2[o]
    int h0i = lane >> 3, h1i = 8 + (lane >> 3);
    float acc0 = B2v[lane], acc1 = B2v[lane + 64];
    const u32* sr0 = &sS[wv][h0i*66];
    const u32* sr1 = &sS[wv][h1i*66];
    #pragma unroll 8
    for (int j = 0; j < 64; ++j) {
        u32 us0 = sr0[j], uw0 = vw2t[j*128 + lane];
        u32 us1 = sr1[j], uw1 = vw2t[j*128 + 64 + lane];
        acc0 += lo16(us0)*lo16(uw0) + hi16(us0)*hi16(uw0);
        acc1 += lo16(us1)*lo16(uw1) + hi16(us1)*hi16(uw1);
    }
    out[(size_t)e*128 + lane] = acc0;
    out[(size_t)e*128 + 64 + lane] = acc1;
}

extern "C" void kernel_launch(void* const* d_in, const int* in_sizes, int n_in,
                              void* d_out, int out_size, void* d_ws, size_t ws_size,
                              hipStream_t stream)
{
    const float* h_bond = (const float*)d_in[1];
    const float* pos    = (const float*)d_in[2];
    const float* hkW1 = (const float*)d_in[3];
    const float* hkb1 = (const float*)d_in[4];
    const float* hkg  = (const float*)d_in[5];
    const float* hkb  = (const float*)d_in[6];
    const float* hkW2 = (const float*)d_in[7];
    const float* hvW1 = (const float*)d_in[9];
    const float* hvb1 = (const float*)d_in[10];
    const float* hvg  = (const float*)d_in[11];
    const float* hvb  = (const float*)d_in[12];
    const float* hvW2 = (const float*)d_in[13];
    const float* hvb2 = (const float*)d_in[14];
    const float* hqW1 = (const float*)d_in[15];
    const float* hqb1 = (const float*)d_in[16];
    const float* hqg  = (const float*)d_in[17];
    const float* hqb  = (const float*)d_in[18];
    const float* hqW2 = (const float*)d_in[19];
    const float* hqb2 = (const float*)d_in[20];
    const int* row    = (const int*)d_in[21];
    const int* col    = (const int*)d_in[22];
    const int* idx_k  = (const int*)d_in[25];
    const int* idx_kj = (const int*)d_in[26];
    const int* idx_ji = (const int*)d_in[27];

    int E = in_sizes[21];
    int T = in_sizes[27];

    char* w = (char*)d_ws;
    size_t off = 0;
    auto carve = [&](size_t bytes) -> void* {
        void* p = w + off;
        off = (off + bytes + 255) & ~(size_t)255;
        return p;
    };
    int*  seg   = (int*) carve(((size_t)E + 1) * sizeof(int));
    bf16* qf    = (bf16*)carve((size_t)E * 128 * sizeof(bf16));
    bf16* P1k   = (bf16*)carve((size_t)E * 128 * sizeof(bf16));
    bf16* P1v   = (bf16*)carve((size_t)E * 128 * sizeof(bf16));
    u32*  kw2t  = (u32*) carve(8192 * sizeof(u32));
    u32*  vw2t  = (u32*) carve(8192 * sizeof(u32));

    if (off > ws_size) {
        marker_kernel<<<(out_size + 255)/256, 256, 0, stream>>>((float*)d_out, out_size);
        return;
    }

    int gq = (E + 15)/16;
    int gw = (E + 3)/4;
    seg_start_kernel<<<(E + 1 + 255)/256, 256, 0, stream>>>(idx_ji, T, seg, E);
    pack_w2<<<32, 256, 0, stream>>>(hkW2, hvW2, kw2t, vw2t);
    q_kernel<<<gq, 128, 0, stream>>>(hqW1, hqb1, hqg, hqb, hqW2, hqb2, h_bond, qf, E);
    p_prep<<<gq, 128, 0, stream>>>(hkW1, h_bond, pos, row, col, P1k, E);
    p_prep<<<gq, 128, 0, stream>>>(hvW1, h_bond, pos, row, col, P1v, E);
    fused_kernel<<<gw, 256, 0, stream>>>(kw2t, vw2t,
        hkW1, hkb1, hkg, hkb,
        hvW1, hvb1, hvg, hvb,
        hvb2, qf, P1k, P1v, pos, seg, idx_kj, idx_k, row, col, (float*)d_out, E);
}

// Round 12
// 1623.054 us; speedup vs baseline: 2.4661x; 1.0237x over previous
//
#include <hip/hip_runtime.h>
#include <hip/hip_bf16.h>
#include <math.h>

typedef __hip_bfloat16 bf16;
typedef unsigned int u32;
typedef float v2f __attribute__((ext_vector_type(2)));

__device__ __forceinline__ float b2f(bf16 x){ return __bfloat162float(x); }
__device__ __forceinline__ bf16  f2b(float x){ return __float2bfloat16(x); }
__device__ __forceinline__ float lo16(u32 u){ return __uint_as_float(u << 16); }
__device__ __forceinline__ float hi16(u32 u){ return __uint_as_float(u & 0xFFFF0000u); }
// float -> bf16 bits with round-to-nearest-even
__device__ __forceinline__ u32 bfbits(float x){
    u32 u = __float_as_uint(x);
    return (u + 0x7FFFu + ((u >> 16) & 1u)) >> 16;
}

#define RSQRT8 0.35355339059327373f
#define G_STEP (10.0f/19.0f)
#define G_COEF (-0.5f/(G_STEP*G_STEP))

// butterfly layout involution: lane l holds head PERM4(l&15); PERM4 is self-inverse
__device__ __forceinline__ constexpr int PERM4(int h){
    return ((h&1)<<3) | ((h&2)<<1) | ((h&4)>>1) | ((h&8)>>3);
}

// fast atan2 for y >= 0 (result in [0, pi]); poly max err ~1.6e-6 rad
__device__ __forceinline__ float fast_atan2(float y, float x){
    float ax = fabsf(x);
    float mn = fminf(y, ax), mx = fmaxf(y, ax);
    float t = mn / fmaxf(mx, 1e-30f);
    float s = t*t;
    float p = t * (0.99997726f + s*(-0.33262347f + s*(0.19354346f +
              s*(-0.11643287f + s*(0.05265332f + s*(-0.01172120f))))));
    float r = (y > ax) ? (1.5707963267948966f - p) : p;
    r = (x < 0.f) ? (3.14159265358979323f - r) : r;
    return r;
}

// inputs are PROVEN f32

// ---------------- seg starts (idx_ji sorted) ----------------
__global__ void seg_start_kernel(const int* __restrict__ idx_ji, int T,
                                 int* __restrict__ seg, int E)
{
    int e = blockIdx.x * blockDim.x + threadIdx.x;
    if (e > E) return;
    int lo = 0, hi = T;
    while (lo < hi) { int mid = (lo + hi) >> 1; if (idx_ji[mid] < e) lo = mid + 1; else hi = mid; }
    seg[e] = lo;
}

__global__ void marker_kernel(float* out, int n){
    int i = blockIdx.x * blockDim.x + threadIdx.x;
    if (i < n) out[i] = 12345.0f;
}

// ---------------- pack W2 matrices to bf16-pair layouts (L2-resident) --------
__global__ void pack_w2(const float* __restrict__ Wk2, const float* __restrict__ Wv2,
                        u32* __restrict__ kw2t, u32* __restrict__ vw2t)
{
    int idx = blockIdx.x*256 + threadIdx.x;
    if (idx >= 8192) return;
    int c = idx >> 6, p = idx & 63;
    kw2t[idx] = bfbits(Wk2[(size_t)(2*p)*128 + c]) | (bfbits(Wk2[(size_t)(2*p+1)*128 + c]) << 16);
    int j = idx >> 7, o = idx & 127;
    vw2t[idx] = bfbits(Wv2[(size_t)(2*j)*128 + o]) | (bfbits(Wv2[(size_t)(2*j+1)*128 + o]) << 16);
}

// ---------------- q = MLP_hq(h_bond) per edge -> bf16, 4-edge batched --------
__global__ __launch_bounds__(128) void q_kernel(
    const float* __restrict__ W1, const float* __restrict__ B1,
    const float* __restrict__ G,  const float* __restrict__ Bln,
    const float* __restrict__ W2, const float* __restrict__ B2,
    const float* __restrict__ h_bond, bf16* __restrict__ qout, int E)
{
    __shared__ u32 sW[128*65];
    __shared__ float sH[16][130];
    __shared__ float sX[4][130];
    __shared__ float sRed[4][4];
    int tid = threadIdx.x; int wv = tid>>6, lane = tid&63;
    int base = blockIdx.x * 16;

    for (int idx = tid; idx < 128*128; idx += 128) {
        int i = idx >> 7, d = idx & 127;
        ((bf16*)sW)[d*130 + i] = f2b(W1[idx]);
    }
    __syncthreads();
    for (int e4 = 0; e4 < 16; e4 += 4) {
        #pragma unroll
        for (int q = 0; q < 4; ++q) {
            int e = base + e4 + q;
            sX[q][tid] = (e < E) ? h_bond[(size_t)e*128 + tid] : 0.f;
        }
        __syncthreads();
        float b1t = B1[tid];
        float ac[4] = {b1t, b1t, b1t, b1t};
        const u32* wrow = &sW[tid*65];
        #pragma unroll 4
        for (int j = 0; j < 64; ++j) {
            u32 w = wrow[j]; float wl = lo16(w), wh = hi16(w);
            #pragma unroll
            for (int q = 0; q < 4; ++q)
                ac[q] += sX[q][2*j]*wl + sX[q][2*j+1]*wh;
        }
        float s1v[4], s2v[4];
        #pragma unroll
        for (int q = 0; q < 4; ++q) { s1v[q] = ac[q]; s2v[q] = ac[q]*ac[q]; }
        #pragma unroll
        for (int m = 1; m < 64; m <<= 1) {
            #pragma unroll
            for (int q = 0; q < 4; ++q) {
                s1v[q] += __shfl_xor(s1v[q], m, 64);
                s2v[q] += __shfl_xor(s2v[q], m, 64);
            }
        }
        if (lane == 0) {
            #pragma unroll
            for (int q = 0; q < 4; ++q) { sRed[q][wv*2] = s1v[q]; sRed[q][wv*2+1] = s2v[q]; }
        }
        __syncthreads();
        float gt = G[tid], bt = Bln[tid];
        #pragma unroll
        for (int q = 0; q < 4; ++q) {
            float tot = sRed[q][0] + sRed[q][2], tot2 = sRed[q][1] + sRed[q][3];
            float mu = tot * (1.f/128.f);
            float var = fmaxf(tot2 * (1.f/128.f) - mu*mu, 0.f);
            float nv = gt * (ac[q] - mu) * rsqrtf(var + 1e-5f) + bt;
            sH[e4+q][tid] = fmaxf(nv, 0.f);
        }
        __syncthreads();
    }
    for (int idx = tid; idx < 128*128; idx += 128) {
        int i = idx >> 7, d = idx & 127;
        ((bf16*)sW)[d*130 + i] = f2b(W2[idx]);
    }
    __syncthreads();
    for (int e4 = 0; e4 < 16; e4 += 4) {
        float b2t = B2[tid];
        float ac[4] = {b2t, b2t, b2t, b2t};
        const u32* wrow = &sW[tid*65];
        #pragma unroll 4
        for (int j = 0; j < 64; ++j) {
            u32 w = wrow[j]; float wl = lo16(w), wh = hi16(w);
            #pragma unroll
            for (int q = 0; q < 4; ++q)
                ac[q] += sH[e4+q][2*j]*wl + sH[e4+q][2*j+1]*wh;
        }
        #pragma unroll
        for (int q = 0; q < 4; ++q) {
            int e = base + e4 + q;
            if (e < E) qout[(size_t)e*128 + tid] = f2b(ac[q]);
        }
    }
}

// ---------------- P1[e] = h_bond[e]@W1[0:128] + rfeat[e]@W1[128:148] -> bf16 --
// R5/R7-proven: LDS-staged weights, 4-edge batched.
__global__ __launch_bounds__(128) void p_prep(
    const float* __restrict__ W1, const float* __restrict__ h_bond,
    const float* __restrict__ pos, const int* __restrict__ row,
    const int* __restrict__ col, bf16* __restrict__ P1, int E)
{
    __shared__ u32 sW[128*75];       // [dim][row-pair], 148 rows -> 74 pairs, stride 150 bf16
    __shared__ float sX[4][152];
    int tid = threadIdx.x;
    for (int idx = tid; idx < 148*128; idx += 128) {
        int i = idx >> 7, d = idx & 127;
        ((bf16*)sW)[d*150 + i] = f2b(W1[idx]);
    }
    __syncthreads();
    int base = blockIdx.x * 16;
    for (int e4 = 0; e4 < 16; e4 += 4) {
        #pragma unroll
        for (int q = 0; q < 4; ++q) {
            int e = base + e4 + q;
            sX[q][tid] = (e < E) ? h_bond[(size_t)e*128 + tid] : 0.f;
        }
        if (tid < 80) {
            int q = tid / 20, g = tid % 20;
            int e = base + e4 + q;
            float rf = 0.f;
            if (e < E) {
                int i0 = col[e], j0 = row[e];
                float dx = pos[(size_t)i0*3+0] - pos[(size_t)j0*3+0];
                float dy = pos[(size_t)i0*3+1] - pos[(size_t)j0*3+1];
                float dz = pos[(size_t)i0*3+2] - pos[(size_t)j0*3+2];
                float dist = sqrtf(dx*dx + dy*dy + dz*dz);
                float t = dist - (float)g * G_STEP;
                rf = __expf(G_COEF * t * t);
            }
            sX[q][128 + g] = rf;
        }
        __syncthreads();
        float acc0 = 0.f, acc1 = 0.f, acc2 = 0.f, acc3 = 0.f;
        const u32* wrow = &sW[tid*75];
        #pragma unroll 4
        for (int j = 0; j < 74; ++j) {
            u32 w = wrow[j]; float wl = lo16(w), wh = hi16(w);
            acc0 += sX[0][2*j]*wl + sX[0][2*j+1]*wh;
            acc1 += sX[1][2*j]*wl + sX[1][2*j+1]*wh;
            acc2 += sX[2][2*j]*wl + sX[2][2*j+1]*wh;
            acc3 += sX[3][2*j]*wl + sX[3][2*j+1]*wh;
        }
        int e = base + e4;
        if (e   < E) P1[(size_t)e*128     + tid] = f2b(acc0);
        if (e+1 < E) P1[(size_t)(e+1)*128 + tid] = f2b(acc1);
        if (e+2 < E) P1[(size_t)(e+2)*128 + tid] = f2b(acc2);
        if (e+3 < E) P1[(size_t)(e+3)*128 + tid] = f2b(acc3);
        __syncthreads();
    }
}

// per-edge P2 pre-act (gaussian part + b1), v2f accumulator (pk-math candidate)
#define EDGE_P2(W1full, Bptr, P2_) \
    v2f P2_ = ((const v2f*)(Bptr))[lane]; \
    { const v2f* wbp = (const v2f*)((W1full) + (size_t)148*128); \
      for (int g2 = 0; g2 < 20; ++g2) { \
        float tg = dist - (float)g2 * G_STEP; \
        float rf = __expf(G_COEF * tg * tg); \
        P2_ += rf * wbp[g2*64 + lane]; \
      } }

// geometry + trig identities for one triplet (suffix S)
#define GEOM(S) \
    float dt##S = ax*bx##S + ay*by##S + az*bz##S; \
    float cxx##S = ay*bz##S - az*by##S, cyy##S = az*bx##S - ax*bz##S, czz##S = ax*by##S - ay*bx##S; \
    float bb##S = cxx##S*cxx##S + cyy##S*cyy##S + czz##S*czz##S; \
    float bc##S = sqrtf(bb##S); \
    float ih##S = rsqrtf(fmaxf(dt##S*dt##S + bb##S, 1e-30f)); \
    float c1##S = dt##S * ih##S, s1##S = bc##S * ih##S; \
    float ang##S = fast_atan2(bc##S, dt##S); \
    float sh##S = sqrtf(fmaxf(0.5f*(1.f - c1##S), 0.f)); \
    float ch##S = sqrtf(fmaxf(0.5f*(1.f + c1##S), 0.f)); \
    float st3##S, ct3##S; __sincosf((1.f/3.f)*ang##S, &st3##S, &ct3##S);

// one feature: two b32 weight reads (R7 layout, conflict-free), v2f FMAs
// (4 v_pk_fma_f32 instead of 8 scalar v_fma_f32 when pk-math forms)
#define FEAT(fidx, valX, valY) { \
    u32 wk_ = sWA[0][(fidx)*64 + lane]; \
    u32 wu_ = sWA[1][(fidx)*64 + lane]; \
    v2f wk2_; wk2_.x = lo16(wk_); wk2_.y = hi16(wk_); \
    v2f wv2_; wv2_.x = lo16(wu_); wv2_.y = hi16(wu_); \
    float fx_ = (valX), fy_ = (valY); \
    vkX += fx_*wk2_; vvX += fx_*wv2_; \
    vkY += fy_*wk2_; vvY += fy_*wv2_; }

// 7-shfl split reduction: (sum, sumsq) over 128 dims
#define LNSTATS(v0_, v1_, TOT, TOT2) { \
    float sum_ = (v0_) + (v1_), ssq_ = (v0_)*(v0_) + (v1_)*(v1_); \
    float r_ = ((lane&1) ? ssq_ : sum_) + __shfl_xor((lane&1) ? sum_ : ssq_, 1, 64); \
    r_ += __shfl_xor(r_, 2, 64);  r_ += __shfl_xor(r_, 4, 64); \
    r_ += __shfl_xor(r_, 8, 64);  r_ += __shfl_xor(r_, 16, 64); \
    r_ += __shfl_xor(r_, 32, 64); \
    float o_ = __shfl_xor(r_, 1, 64); \
    TOT = (lane&1) ? o_ : r_;  TOT2 = (lane&1) ? r_ : o_; }

// LN apply on a v2f pre-activation (vector math except the relu clamps)
#define LNAPPLY(TOT, TOT2, vv_, g2_, b2_, H) { \
    float mu_ = (TOT) * (1.f/128.f); \
    float var_ = fmaxf((TOT2) * (1.f/128.f) - mu_*mu_, 0.f); \
    float rs_ = rsqrtf(var_ + 1e-5f); \
    v2f t_ = g2_*(vv_ - mu_)*rs_ + b2_; \
    H.x = fmaxf(t_.x, 0.f); H.y = fmaxf(t_.y, 0.f); }

// 17-shfl split-exchange butterfly: 16 reductions -> LG (head PERM4(lane&15))
#define BFLY(P, LG) { \
    float a8_[8]; \
    { int up_ = lane & 1; \
      _Pragma("unroll") \
      for (int i_ = 0; i_ < 8; ++i_) { \
        float kp_ = up_ ? P[i_+8] : P[i_]; \
        float sd_ = up_ ? P[i_]   : P[i_+8]; \
        a8_[i_] = kp_ + __shfl_xor(sd_, 1, 64); } } \
    float a4_[4]; \
    { int up_ = lane & 2; \
      _Pragma("unroll") \
      for (int i_ = 0; i_ < 4; ++i_) { \
        float kp_ = up_ ? a8_[i_+4] : a8_[i_]; \
        float sd_ = up_ ? a8_[i_]   : a8_[i_+4]; \
        a4_[i_] = kp_ + __shfl_xor(sd_, 2, 64); } } \
    float a2_[2]; \
    { int up_ = lane & 4; \
      _Pragma("unroll") \
      for (int i_ = 0; i_ < 2; ++i_) { \
        float kp_ = up_ ? a4_[i_+2] : a4_[i_]; \
        float sd_ = up_ ? a4_[i_]   : a4_[i_+2]; \
        a2_[i_] = kp_ + __shfl_xor(sd_, 4, 64); } } \
    float a1_; \
    { int up_ = lane & 8; \
      float kp_ = up_ ? a2_[1] : a2_[0]; \
      float sd_ = up_ ? a2_[0] : a2_[1]; \
      a1_ = kp_ + __shfl_xor(sd_, 8, 64); } \
    a1_ += __shfl_xor(a1_, 16, 64); \
    a1_ += __shfl_xor(a1_, 32, 64); \
    LG = a1_ * RSQRT8; }

// ---------------- fused: logits + online softmax + v-path + projection -------
// R12: R7's exact structure (953us best; b32 sWA reads - R11's b64 packing
// caused 880k bank conflicts and regressed) with the pairwise (dim0,dim1)
// arithmetic expressed as ext_vector float2 -> <2 x float> IR -> v_pk_fma_f32
// on gfx950. Halves ~180 of ~550 VALU insts/pair if pk-math forms; degenerates
// to R7's scalar codegen (parity) if scalarized. No layout/live-set change.
__global__ __launch_bounds__(256, 2)
void fused_kernel(
    const u32* __restrict__ kw2t, const u32* __restrict__ vw2t,
    const float* __restrict__ Wk1, const float* __restrict__ Bk1,
    const float* __restrict__ Gkg, const float* __restrict__ Bkln,
    const float* __restrict__ Wv1, const float* __restrict__ Bv1,
    const float* __restrict__ Gvg, const float* __restrict__ Bvln,
    const float* __restrict__ B2v,
    const bf16* __restrict__ qf, const bf16* __restrict__ P1k, const bf16* __restrict__ P1v,
    const float* __restrict__ pos, const int* __restrict__ seg,
    const int* __restrict__ idx_kj, const int* __restrict__ idx_k,
    const int* __restrict__ row, const int* __restrict__ col,
    float* __restrict__ out, int E)
{
    __shared__ u32 sS[4][16*66];     // epilogue staging; loop-time overlay holds Gk
    __shared__ u32 sWA[2][11*64];    // deduped angular weight pairs: [path][f][lane]
    __shared__ float2 sEx[4][16];    // per-wave (exX, exY) per head
    int tid = threadIdx.x, lane = tid & 63, wv = tid >> 6;

    // block-cooperative populate of sWA. Feature order:
    // {ang, s1, s2, s3, sh, st3, c1, c2, c3, ch, ct3}; s1 at {1,4}, c1 at {7,10} folded.
    if (tid < 128) {
        int path = tid >> 6, l = tid & 63;
        const float* W1full = path ? Wv1 : Wk1;
        const float2* wap = (const float2*)(W1full + (size_t)168*128);
        float2 w0  = wap[ 0*64 + l];
        float2 w1  = wap[ 1*64 + l];
        float2 w2  = wap[ 2*64 + l];
        float2 w3  = wap[ 3*64 + l];
        float2 w4  = wap[ 4*64 + l];
        float2 w5  = wap[ 5*64 + l];
        float2 w6  = wap[ 6*64 + l];
        float2 w7  = wap[ 7*64 + l];
        float2 w8  = wap[ 8*64 + l];
        float2 w9  = wap[ 9*64 + l];
        float2 w10 = wap[10*64 + l];
        float2 w11 = wap[11*64 + l];
        float2 w12 = wap[12*64 + l];
        u32* dst = &sWA[path][0];
        dst[ 0*64 + l] = bfbits(w0.x)       | (bfbits(w0.y)       << 16);
        dst[ 1*64 + l] = bfbits(w1.x+w4.x)  | (bfbits(w1.y+w4.y)  << 16);
        dst[ 2*64 + l] = bfbits(w2.x)       | (bfbits(w2.y)       << 16);
        dst[ 3*64 + l] = bfbits(w3.x)       | (bfbits(w3.y)       << 16);
        dst[ 4*64 + l] = bfbits(w5.x)       | (bfbits(w5.y)       << 16);
        dst[ 5*64 + l] = bfbits(w6.x)       | (bfbits(w6.y)       << 16);
        dst[ 6*64 + l] = bfbits(w7.x+w10.x) | (bfbits(w7.y+w10.y) << 16);
        dst[ 7*64 + l] = bfbits(w8.x)       | (bfbits(w8.y)       << 16);
        dst[ 8*64 + l] = bfbits(w9.x)       | (bfbits(w9.y)       << 16);
        dst[ 9*64 + l] = bfbits(w11.x)      | (bfbits(w11.y)      << 16);
        dst[10*64 + l] = bfbits(w12.x)      | (bfbits(w12.y)      << 16);
    }
    __syncthreads();                 // ONLY barrier; before any divergent return

    int e = __builtin_amdgcn_readfirstlane(blockIdx.x*4 + wv);
    if (e >= E) return;
    int s0 = __builtin_amdgcn_readfirstlane(seg[e]);
    int s1 = __builtin_amdgcn_readfirstlane(seg[e+1]);
    if (s1 <= s0) { out[(size_t)e*128 + lane] = 0.f; out[(size_t)e*128 + 64 + lane] = 0.f; return; }

    v2f gk2 = ((const v2f*)Gkg)[lane];
    v2f bk2 = ((const v2f*)Bkln)[lane];
    v2f gv2 = ((const v2f*)Gvg)[lane];
    v2f bv2 = ((const v2f*)Bvln)[lane];

    int i0 = __builtin_amdgcn_readfirstlane(col[e]);
    int j0 = __builtin_amdgcn_readfirstlane(row[e]);
    float pix = pos[(size_t)i0*3+0], piy = pos[(size_t)i0*3+1], piz = pos[(size_t)i0*3+2];
    float pjx = pos[(size_t)j0*3+0], pjy = pos[(size_t)j0*3+1], pjz = pos[(size_t)j0*3+2];
    float dxx = pix-pjx, dyy = piy-pjy, dzz = piz-pjz;
    float dist = sqrtf(dxx*dxx + dyy*dyy + dzz*dzz);

    EDGE_P2(Wk1, Bk1, P2k);
    EDGE_P2(Wv1, Bv1, P2v);

    // Gk[h] packed bf16 pair -> per-wave LDS (overlay on sS; loop-only lifetime)
    u32* sGkw = &sS[wv][0];          // needs 16*64 u32 <= 16*66 available
    {
        const u32* qrow = (const u32*)(qf + (size_t)e*128);
        #pragma unroll
        for (int h = 0; h < 16; ++h) {
            float g0 = 0.f, g1 = 0.f;
            #pragma unroll
            for (int j = 0; j < 4; ++j) {
                u32 qp = qrow[h*4 + j];
                float ql = lo16(qp), qh = hi16(qp);
                u32 w0 = kw2t[(h*8 + 2*j)*64 + lane];
                u32 w1 = kw2t[(h*8 + 2*j + 1)*64 + lane];
                g0 += ql*lo16(w0) + qh*lo16(w1);
                g1 += ql*hi16(w0) + qh*hi16(w1);
            }
            sGkw[h*64 + lane] = bfbits(g0) | (bfbits(g1) << 16);
        }
    }

    v2f S[16];
    #pragma unroll
    for (int h = 0; h < 16; ++h) S[h] = (v2f)(0.f);
    float m = -1e30f, sden = 0.f;

    const u32* p1ku = (const u32*)P1k;
    const u32* p1vu = (const u32*)P1v;
    float ax = pjx-pix, ay = pjy-piy, az = pjz-piz;
    int perm = ((lane&1)<<3) | ((lane&2)<<1) | ((lane&4)>>1) | ((lane&8)>>3);

    // 2-ahead prefetch state for triplet pair (X, Y)
    int tB0 = (s0+1 < s1) ? s0+1 : s0;
    int kjX = __builtin_amdgcn_readfirstlane(idx_kj[s0]);
    int knX = __builtin_amdgcn_readfirstlane(idx_k[s0]);
    int kjY = __builtin_amdgcn_readfirstlane(idx_kj[tB0]);
    int knY = __builtin_amdgcn_readfirstlane(idx_k[tB0]);
    u32 fppkX = p1ku[(size_t)kjX*64 + lane], fppvX = p1vu[(size_t)kjX*64 + lane];
    u32 fppkY = p1ku[(size_t)kjY*64 + lane], fppvY = p1vu[(size_t)kjY*64 + lane];
    float fpkxX = pos[(size_t)knX*3+0], fpkyX = pos[(size_t)knX*3+1], fpkzX = pos[(size_t)knX*3+2];
    float fpkxY = pos[(size_t)knY*3+0], fpkyY = pos[(size_t)knY*3+1], fpkzY = pos[(size_t)knY*3+2];

    for (int t = s0; t < s1; t += 2) {
        const bool twoY = (t+1 < s1);
        // consume prefetched
        u32 ppkX = fppkX, ppvX = fppvX, ppkY = fppkY, ppvY = fppvY;
        float bxX = fpkxX-pix, byX = fpkyX-piy, bzX = fpkzX-piz;
        float bxY = fpkxY-pix, byY = fpkyY-piy, bzY = fpkzY-piz;
        // issue next-pair prefetch (clamped; duplicates harmless)
        int tn0 = (t+2 < s1) ? t+2 : s1-1;
        int tn1 = (t+3 < s1) ? t+3 : s1-1;
        kjX = __builtin_amdgcn_readfirstlane(idx_kj[tn0]);
        knX = __builtin_amdgcn_readfirstlane(idx_k[tn0]);
        kjY = __builtin_amdgcn_readfirstlane(idx_kj[tn1]);
        knY = __builtin_amdgcn_readfirstlane(idx_k[tn1]);
        fppkX = p1ku[(size_t)kjX*64 + lane]; fppvX = p1vu[(size_t)kjX*64 + lane];
        fppkY = p1ku[(size_t)kjY*64 + lane]; fppvY = p1vu[(size_t)kjY*64 + lane];
        fpkxX = pos[(size_t)knX*3+0]; fpkyX = pos[(size_t)knX*3+1]; fpkzX = pos[(size_t)knX*3+2];
        fpkxY = pos[(size_t)knY*3+0]; fpkyY = pos[(size_t)knY*3+1]; fpkzY = pos[(size_t)knY*3+2];

        GEOM(X);
        GEOM(Y);

        // pre-activations: k/v paths x triplets X/Y (v2f = (dim0, dim1))
        v2f vkX = P2k; vkX.x += lo16(ppkX); vkX.y += hi16(ppkX);
        v2f vvX = P2v; vvX.x += lo16(ppvX); vvX.y += hi16(ppvX);
        v2f vkY = P2k; vkY.x += lo16(ppkY); vkY.y += hi16(ppkY);
        v2f vvY = P2v; vvY.x += lo16(ppvY); vvY.y += hi16(ppvY);

        FEAT(0,  angX, angY);
        FEAT(1,  s1X,  s1Y);
        FEAT(2,  2.f*s1X*c1X, 2.f*s1Y*c1Y);
        FEAT(3,  s1X*(3.f - 4.f*s1X*s1X), s1Y*(3.f - 4.f*s1Y*s1Y));
        FEAT(4,  shX,  shY);
        FEAT(5,  st3X, st3Y);
        FEAT(6,  c1X,  c1Y);
        FEAT(7,  1.f - 2.f*s1X*s1X, 1.f - 2.f*s1Y*s1Y);
        FEAT(8,  c1X*(4.f*c1X*c1X - 3.f), c1Y*(4.f*c1Y*c1Y - 3.f));
        FEAT(9,  chX,  chY);
        FEAT(10, ct3X, ct3Y);

        // 4 independent LN chains (compiler interleaves)
        float totKX, tot2KX, totVX, tot2VX, totKY, tot2KY, totVY, tot2VY;
        LNSTATS(vkX.x, vkX.y, totKX, tot2KX);
        LNSTATS(vvX.x, vvX.y, totVX, tot2VX);
        LNSTATS(vkY.x, vkY.y, totKY, tot2KY);
        LNSTATS(vvY.x, vvY.y, totVY, tot2VY);
        v2f hkX, hvX, hkY, hvY;
        LNAPPLY(totKX, tot2KX, vkX, gk2, bk2, hkX);
        LNAPPLY(totVX, tot2VX, vvX, gv2, bv2, hvX);
        LNAPPLY(totKY, tot2KY, vkY, gk2, bk2, hkY);
        LNAPPLY(totVY, tot2VY, vvY, gv2, bv2, hvY);

        // per-head logit partials (Gk from per-wave LDS, read once for X and Y)
        float pX[16], pY[16];
        #pragma unroll
        for (int h = 0; h < 16; ++h) {
            u32 g = sGkw[h*64 + lane];
            float gl = lo16(g), gh = hi16(g);
            pX[h] = hkX.x*gl + hkX.y*gh;
            pY[h] = hkY.x*gl + hkY.y*gh;
        }
        float lgX, lgY;
        BFLY(pX, lgX);
        BFLY(pY, lgY);

        // online softmax (pair): one deferred-max check covers both logits
        float mx = fmaxf(lgX, lgY);
        if (__any(mx > m + 8.f)) {
            float nm = fmaxf(m, mx);
            float fac = __expf(m - nm);
            sden *= fac; m = nm;
            #pragma unroll
            for (int h = 0; h < 16; ++h) {
                float fh = __shfl(fac, PERM4(h), 64);
                S[h] *= fh;
            }
        }
        float exX = __expf(lgX - m);
        float exY = twoY ? __expf(lgY - m) : 0.f;   // masked tail: no double count
        sden += exX + exY;
        // broadcast via per-wave LDS (replaces 16 ds_bpermute)
        if (lane < 16) sEx[wv][perm] = make_float2(exX, exY);
        #pragma unroll
        for (int h = 0; h < 16; ++h) {
            float2 eh = sEx[wv][h];
            S[h] += eh.x*hvX + eh.y*hvY;
        }
    }

    // normalize by softmax denominator while staging S as bf16 pairs
    float inv = 1.f / sden;
    #pragma unroll
    for (int h = 0; h < 16; ++h) {
        float sc = __shfl(inv, PERM4(h), 64);
        v2f sv = S[h] * sc;
        sS[wv][h*66 + lane] = bfbits(sv.x) | (bfbits(sv.y) << 16);
    }
    __threadfence_block();
    // projection: out[o] = sum_d S[o>>3][d]*Wv2[d][o] + b2[o]
    int h0i = lane >> 3, h1i = 8 + (lane >> 3);
    float acc0 = B2v[lane], acc1 = B2v[lane + 64];
    const u32* sr0 = &sS[wv][h0i*66];
    const u32* sr1 = &sS[wv][h1i*66];
    #pragma unroll 8
    for (int j = 0; j < 64; ++j) {
        u32 us0 = sr0[j], uw0 = vw2t[j*128 + lane];
        u32 us1 = sr1[j], uw1 = vw2t[j*128 + 64 + lane];
        acc0 += lo16(us0)*lo16(uw0) + hi16(us0)*hi16(uw0);
        acc1 += lo16(us1)*lo16(uw1) + hi16(us1)*hi16(uw1);
    }
    out[(size_t)e*128 + lane] = acc0;
    out[(size_t)e*128 + 64 + lane] = acc1;
}

extern "C" void kernel_launch(void* const* d_in, const int* in_sizes, int n_in,
                              void* d_out, int out_size, void* d_ws, size_t ws_size,
                              hipStream_t stream)
{
    const float* h_bond = (const float*)d_in[1];
    const float* pos    = (const float*)d_in[2];
    const float* hkW1 = (const float*)d_in[3];
    const float* hkb1 = (const float*)d_in[4];
    const float* hkg  = (const float*)d_in[5];
    const float* hkb  = (const float*)d_in[6];
    const float* hkW2 = (const float*)d_in[7];
    const float* hvW1 = (const float*)d_in[9];
    const float* hvb1 = (const float*)d_in[10];
    const float* hvg  = (const float*)d_in[11];
    const float* hvb  = (const float*)d_in[12];
    const float* hvW2 = (const float*)d_in[13];
    const float* hvb2 = (const float*)d_in[14];
    const float* hqW1 = (const float*)d_in[15];
    const float* hqb1 = (const float*)d_in[16];
    const float* hqg  = (const float*)d_in[17];
    const float* hqb  = (const float*)d_in[18];
    const float* hqW2 = (const float*)d_in[19];
    const float* hqb2 = (const float*)d_in[20];
    const int* row    = (const int*)d_in[21];
    const int* col    = (const int*)d_in[22];
    const int* idx_k  = (const int*)d_in[25];
    const int* idx_kj = (const int*)d_in[26];
    const int* idx_ji = (const int*)d_in[27];

    int E = in_sizes[21];
    int T = in_sizes[27];

    char* w = (char*)d_ws;
    size_t off = 0;
    auto carve = [&](size_t bytes) -> void* {
        void* p = w + off;
        off = (off + bytes + 255) & ~(size_t)255;
        return p;
    };
    int*  seg   = (int*) carve(((size_t)E + 1) * sizeof(int));
    bf16* qf    = (bf16*)carve((size_t)E * 128 * sizeof(bf16));
    bf16* P1k   = (bf16*)carve((size_t)E * 128 * sizeof(bf16));
    bf16* P1v   = (bf16*)carve((size_t)E * 128 * sizeof(bf16));
    u32*  kw2t  = (u32*) carve(8192 * sizeof(u32));
    u32*  vw2t  = (u32*) carve(8192 * sizeof(u32));

    if (off > ws_size) {
        marker_kernel<<<(out_size + 255)/256, 256, 0, stream>>>((float*)d_out, out_size);
        return;
    }

    int gq = (E + 15)/16;
    int gw = (E + 3)/4;
    seg_start_kernel<<<(E + 1 + 255)/256, 256, 0, stream>>>(idx_ji, T, seg, E);
    pack_w2<<<32, 256, 0, stream>>>(hkW2, hvW2, kw2t, vw2t);
    q_kernel<<<gq, 128, 0, stream>>>(hqW1, hqb1, hqg, hqb, hqW2, hqb2, h_bond, qf, E);
    p_prep<<<gq, 128, 0, stream>>>(hkW1, h_bond, pos, row, col, P1k, E);
    p_prep<<<gq, 128, 0, stream>>>(hvW1, h_bond, pos, row, col, P1v, E);
    fused_kernel<<<gw, 256, 0, stream>>>(kw2t, vw2t,
        hkW1, hkb1, hkg, hkb,
        hvW1, hvb1, hvg, hvb,
        hvb2, qf, P1k, P1v, pos, seg, idx_kj, idx_k, row, col, (float*)d_out, E);
}